// Round 1
// baseline (3056.856 us; speedup 1.0000x reference)
//
#include <hip/hip_runtime.h>
#include <stdint.h>

// ---------------- problem constants ----------------
#define B_    16
#define C1_   512
#define C2_   1024
#define H2_   14
#define D_    1536
#define P_    784          // 28*28
#define N_    12544        // B_*P_
#define M_    15000
#define MPAD_ 15104        // 118*128
#define MT_   118          // m tiles of 128
#define NT_   98           // patch tiles of 128
#define IMG_  224
#define KS_   33

typedef unsigned short u16;
typedef unsigned int   u32;
typedef unsigned long long u64;

// ---------------- helpers ----------------
__device__ __forceinline__ u16 f2bf(float x) {
    u32 u = __float_as_uint(x);
    u = u + 0x7fffu + ((u >> 16) & 1u);   // RNE
    return (u16)(u >> 16);
}
__device__ __forceinline__ float bf2f(u16 h) {
    return __uint_as_float(((u32)h) << 16);
}
// monotone float->uint map (total order), and inverse
__device__ __forceinline__ u32 ordf(float f) {
    u32 u = __float_as_uint(f);
    return (u & 0x80000000u) ? ~u : (u | 0x80000000u);
}
__device__ __forceinline__ float unordf(u32 o) {
    u32 u = (o & 0x80000000u) ? (o ^ 0x80000000u) : ~o;
    return __uint_as_float(u);
}

// ---------------- avg-pool feat2 -> pooled2 [16,1024,14,14] ----------------
__global__ void k_pool2(const float* __restrict__ feat2, float* __restrict__ pooled2) {
    int idx = blockIdx.x * 256 + threadIdx.x;
    if (idx >= B_ * C2_ * H2_ * H2_) return;
    int x = idx % 14, y = (idx / 14) % 14, bc = idx / 196;
    const float* src = feat2 + (size_t)bc * 196;
    float s = 0.f;
    for (int dy = -1; dy <= 1; ++dy) {
        int yy = y + dy; if (yy < 0 || yy > 13) continue;
        for (int dx = -1; dx <= 1; ++dx) {
            int xx = x + dx; if (xx < 0 || xx > 13) continue;
            s += src[yy * 14 + xx];
        }
    }
    pooled2[idx] = s * (1.f / 9.f);
}

// ---------------- bank split (hi/lo bf16) + norms, with padding ----------------
__global__ void k_bank(const float* __restrict__ bank, u16* __restrict__ Bh,
                       u16* __restrict__ Bl, float* __restrict__ ynorm) {
    int m = blockIdx.x, tid = threadIdx.x;
    float nrm = 0.f;
    if (m < M_) {
        for (int p = 0; p < 6; ++p) {
            int c = p * 256 + tid;
            float v = bank[(size_t)m * D_ + c];
            u16 h = f2bf(v);
            Bh[(size_t)m * D_ + c] = h;
            Bl[(size_t)m * D_ + c] = f2bf(v - bf2f(h));
            nrm += v * v;
        }
    } else {
        for (int p = 0; p < 6; ++p) {
            int c = p * 256 + tid;
            Bh[(size_t)m * D_ + c] = 0; Bl[(size_t)m * D_ + c] = 0;
        }
    }
    __shared__ float red[4];
    for (int off = 32; off; off >>= 1) nrm += __shfl_down(nrm, off, 64);
    int wave = tid >> 6, lane = tid & 63;
    if (lane == 0) red[wave] = nrm;
    __syncthreads();
    if (tid == 0) {
        float t = red[0] + red[1] + red[2] + red[3];
        ynorm[m] = (m < M_) ? t : __uint_as_float(0x7f800000u);  // +inf pad
    }
}

// ---------------- embedding build: pool(feat1) ++ bilinear(pooled2), split, norms ----------------
__global__ void k_embed(const float* __restrict__ feat1, const float* __restrict__ pooled2,
                        u16* __restrict__ Ah, u16* __restrict__ Al, float* __restrict__ xnorm) {
    int n = blockIdx.x, tid = threadIdx.x;
    int b = n / P_, p = n % P_, y = p / 28, x = p % 28;
    // bilinear 14->28, half-pixel, clamped (== jax renormalized triangle)
    float sy = y * 0.5f - 0.25f, sx = x * 0.5f - 0.25f;
    int iy = (int)floorf(sy), ix = (int)floorf(sx);
    float fy = sy - iy, fx = sx - ix;
    int y0 = min(max(iy, 0), 13), y1 = min(max(iy + 1, 0), 13);
    int x0 = min(max(ix, 0), 13), x1 = min(max(ix + 1, 0), 13);
    float nrm = 0.f;
    for (int pp = 0; pp < 6; ++pp) {
        int c = pp * 256 + tid;
        float v;
        if (c < C1_) {
            const float* src = feat1 + ((size_t)(b * C1_ + c)) * 784;
            float s = 0.f;
            for (int dy = -1; dy <= 1; ++dy) {
                int yy = y + dy; if (yy < 0 || yy > 27) continue;
                for (int dx = -1; dx <= 1; ++dx) {
                    int xx = x + dx; if (xx < 0 || xx > 27) continue;
                    s += src[yy * 28 + xx];
                }
            }
            v = s * (1.f / 9.f);
        } else {
            const float* sp = pooled2 + ((size_t)(b * C2_ + (c - C1_))) * 196;
            float v00 = sp[y0 * 14 + x0], v01 = sp[y0 * 14 + x1];
            float v10 = sp[y1 * 14 + x0], v11 = sp[y1 * 14 + x1];
            v = (1.f - fy) * ((1.f - fx) * v00 + fx * v01) + fy * ((1.f - fx) * v10 + fx * v11);
        }
        u16 h = f2bf(v);
        Ah[(size_t)n * D_ + c] = h;
        Al[(size_t)n * D_ + c] = f2bf(v - bf2f(h));
        nrm += v * v;
    }
    __shared__ float red[4];
    for (int off = 32; off; off >>= 1) nrm += __shfl_down(nrm, off, 64);
    int wave = tid >> 6, lane = tid & 63;
    if (lane == 0) red[wave] = nrm;
    __syncthreads();
    if (tid == 0) xnorm[n] = red[0] + red[1] + red[2] + red[3];
}

// ---------------- split-bf16 GEMM + fused min/argmin epilogue ----------------
typedef __bf16 bf16x8 __attribute__((ext_vector_type(8)));
typedef float  f32x16 __attribute__((ext_vector_type(16)));

__global__ __launch_bounds__(256)
void k_gemm(const u16* __restrict__ Ah, const u16* __restrict__ Al,
            const u16* __restrict__ Bh, const u16* __restrict__ Bl,
            const float* __restrict__ ynorm, u64* __restrict__ part) {
    __shared__ u16 sA[2][128 * 32];
    __shared__ u16 sB[2][128 * 32];
    __shared__ u64 smin[128][2];

    const int tid = threadIdx.x;
    const int lane = tid & 63, wave = tid >> 6;
    const int mt = blockIdx.x, pt = blockIdx.y;
    const int p0 = pt * 128, m0 = mt * 128;

    f32x16 acc[2][2];
#pragma unroll
    for (int i = 0; i < 2; ++i)
#pragma unroll
        for (int j = 0; j < 2; ++j)
#pragma unroll
            for (int e = 0; e < 16; ++e) acc[i][j][e] = 0.f;

    const int srow = lane >> 2;          // 0..15 within slab
    const int scol = (lane & 3) * 8;     // 0,8,16,24 elements
    const int wr = (wave >> 1) * 64, wc = (wave & 1) * 64;
    const int rA = lane & 31, kh = (lane >> 5) * 8;

    for (int kt = 0; kt < 48; ++kt) {
        const int k0 = kt * 32;
        // ---- stage 4 tiles via global_load_lds (16B/lane, wave-uniform LDS base) ----
#pragma unroll
        for (int s = 0; s < 2; ++s) {
            const int slab = wave * 2 + s;
            const int row = slab * 16 + srow;
            const u16* ga = Ah + (size_t)(p0 + row) * D_ + k0 + scol;
            __builtin_amdgcn_global_load_lds((const __attribute__((address_space(1))) void*)ga,
                (__attribute__((address_space(3))) void*)&sA[0][slab * 512], 16, 0, 0);
            const u16* ga2 = Al + (size_t)(p0 + row) * D_ + k0 + scol;
            __builtin_amdgcn_global_load_lds((const __attribute__((address_space(1))) void*)ga2,
                (__attribute__((address_space(3))) void*)&sA[1][slab * 512], 16, 0, 0);
            const u16* gb = Bh + (size_t)(m0 + row) * D_ + k0 + scol;
            __builtin_amdgcn_global_load_lds((const __attribute__((address_space(1))) void*)gb,
                (__attribute__((address_space(3))) void*)&sB[0][slab * 512], 16, 0, 0);
            const u16* gb2 = Bl + (size_t)(m0 + row) * D_ + k0 + scol;
            __builtin_amdgcn_global_load_lds((const __attribute__((address_space(1))) void*)gb2,
                (__attribute__((address_space(3))) void*)&sB[1][slab * 512], 16, 0, 0);
        }
        __syncthreads();
        // ---- compute: 2 k-steps of 16, 2x2 tiles of 32x32, 3 hi/lo combos ----
#pragma unroll
        for (int ks = 0; ks < 2; ++ks) {
            const int ko = ks * 16 + kh;
            bf16x8 ah0 = *(const bf16x8*)&sA[0][(wr + rA) * 32 + ko];
            bf16x8 ah1 = *(const bf16x8*)&sA[0][(wr + 32 + rA) * 32 + ko];
            bf16x8 al0 = *(const bf16x8*)&sA[1][(wr + rA) * 32 + ko];
            bf16x8 al1 = *(const bf16x8*)&sA[1][(wr + 32 + rA) * 32 + ko];
            bf16x8 bh0 = *(const bf16x8*)&sB[0][(wc + rA) * 32 + ko];
            bf16x8 bh1 = *(const bf16x8*)&sB[0][(wc + 32 + rA) * 32 + ko];
            bf16x8 bl0 = *(const bf16x8*)&sB[1][(wc + rA) * 32 + ko];
            bf16x8 bl1 = *(const bf16x8*)&sB[1][(wc + 32 + rA) * 32 + ko];
            acc[0][0] = __builtin_amdgcn_mfma_f32_32x32x16_bf16(ah0, bh0, acc[0][0], 0, 0, 0);
            acc[0][1] = __builtin_amdgcn_mfma_f32_32x32x16_bf16(ah0, bh1, acc[0][1], 0, 0, 0);
            acc[1][0] = __builtin_amdgcn_mfma_f32_32x32x16_bf16(ah1, bh0, acc[1][0], 0, 0, 0);
            acc[1][1] = __builtin_amdgcn_mfma_f32_32x32x16_bf16(ah1, bh1, acc[1][1], 0, 0, 0);
            acc[0][0] = __builtin_amdgcn_mfma_f32_32x32x16_bf16(ah0, bl0, acc[0][0], 0, 0, 0);
            acc[0][1] = __builtin_amdgcn_mfma_f32_32x32x16_bf16(ah0, bl1, acc[0][1], 0, 0, 0);
            acc[1][0] = __builtin_amdgcn_mfma_f32_32x32x16_bf16(ah1, bl0, acc[1][0], 0, 0, 0);
            acc[1][1] = __builtin_amdgcn_mfma_f32_32x32x16_bf16(ah1, bl1, acc[1][1], 0, 0, 0);
            acc[0][0] = __builtin_amdgcn_mfma_f32_32x32x16_bf16(al0, bh0, acc[0][0], 0, 0, 0);
            acc[0][1] = __builtin_amdgcn_mfma_f32_32x32x16_bf16(al0, bh1, acc[0][1], 0, 0, 0);
            acc[1][0] = __builtin_amdgcn_mfma_f32_32x32x16_bf16(al1, bh0, acc[1][0], 0, 0, 0);
            acc[1][1] = __builtin_amdgcn_mfma_f32_32x32x16_bf16(al1, bh1, acc[1][1], 0, 0, 0);
        }
        __syncthreads();
    }

    // ---- epilogue: t = ynorm[col] - 2*acc ; min+argmin over this block's 128 cols ----
    const int wrB = wave >> 1, wcB = wave & 1;
    const int half = lane >> 5, c32 = lane & 31;
    float yn[2];
    yn[0] = ynorm[m0 + wcB * 64 + c32];
    yn[1] = ynorm[m0 + wcB * 64 + 32 + c32];
#pragma unroll
    for (int ti = 0; ti < 2; ++ti) {
#pragma unroll
        for (int reg = 0; reg < 16; ++reg) {
            const int rloc = wrB * 64 + ti * 32 + 4 * half + (reg & 3) + 8 * (reg >> 2);
            u64 best = ~0ull;
#pragma unroll
            for (int tj = 0; tj < 2; ++tj) {
                float v = yn[tj] - 2.0f * acc[ti][tj][reg];
                u32 col = (u32)(m0 + wcB * 64 + tj * 32 + c32);
                u64 pk = ((u64)ordf(v) << 32) | col;
                best = pk < best ? pk : best;
            }
#pragma unroll
            for (int msk = 1; msk < 32; msk <<= 1) {
                u64 o = __shfl_xor(best, msk, 64);
                best = o < best ? o : best;
            }
            if (c32 == 0) smin[rloc][wcB] = best;
        }
    }
    __syncthreads();
    if (tid < 128) {
        u64 a = smin[tid][0], b = smin[tid][1];
        part[(size_t)mt * N_ + p0 + tid] = a < b ? a : b;
    }
}

// ---------------- reduce partials over 118 m-tiles ----------------
__global__ void k_reduce(const u64* __restrict__ part, const float* __restrict__ xnorm,
                         float* __restrict__ ps, int* __restrict__ loc) {
    int n = blockIdx.x * 128 + threadIdx.x;
    u64 best = ~0ull;
    for (int t = 0; t < MT_; ++t) {
        u64 v = part[(size_t)t * N_ + n];
        best = v < best ? v : best;
    }
    float val = unordf((u32)(best >> 32));
    ps[n] = sqrtf(fmaxf(val + xnorm[n], 0.f));
    loc[n] = (int)(u32)best;
}

// ---------------- per-image argmax of patch scores ----------------
__global__ void k_argmax(const float* __restrict__ ps, const int* __restrict__ loc,
                         int* __restrict__ mprow, int* __restrict__ nnidx,
                         float* __restrict__ score) {
    int b = blockIdx.x, tid = threadIdx.x;
    u64 best = 0;
    for (int p = tid; p < P_; p += 256) {
        float v = ps[b * P_ + p];
        u64 pk = ((u64)ordf(v) << 32) | (u32)(~(u32)p);   // tie -> lowest p
        best = pk > best ? pk : best;
    }
    for (int msk = 1; msk < 64; msk <<= 1) {
        u64 o = __shfl_xor(best, msk, 64);
        best = o > best ? o : best;
    }
    __shared__ u64 red[4];
    int wave = tid >> 6, lane = tid & 63;
    if (lane == 0) red[wave] = best;
    __syncthreads();
    if (tid == 0) {
        u64 m = red[0];
        for (int w = 1; w < 4; ++w) m = red[w] > m ? red[w] : m;
        int p = (int)(~(u32)m);
        mprow[b] = b * P_ + p;
        nnidx[b] = loc[b * P_ + p];
        score[b] = unordf((u32)(m >> 32));
    }
}

// ---------------- d_nb: dist(bank[nn_index[b]], bank) exact fp32 ----------------
__global__ void k_dnb(const float* __restrict__ bank, const float* __restrict__ ynorm,
                      const int* __restrict__ nnidx, float* __restrict__ dnb) {
    int b = blockIdx.y;
    int wave = threadIdx.x >> 6, lane = threadIdx.x & 63;
    int nn = nnidx[b];
    const float4* nr = (const float4*)(bank + (size_t)nn * D_);
    float ynn = ynorm[nn];
    for (int it = 0; it < 16; ++it) {
        int m = blockIdx.x * 64 + wave * 16 + it;
        if (m >= M_) continue;
        const float4* br = (const float4*)(bank + (size_t)m * D_);
        float acc = 0.f;
#pragma unroll
        for (int p = 0; p < 6; ++p) {
            float4 a = nr[p * 64 + lane];
            float4 c = br[p * 64 + lane];
            acc += a.x * c.x + a.y * c.y + a.z * c.z + a.w * c.w;
        }
        for (int msk = 1; msk < 64; msk <<= 1) acc += __shfl_xor(acc, msk, 64);
        if (lane == 0) dnb[b * M_ + m] = sqrtf(fmaxf(ynn - 2.f * acc + ynorm[m], 0.f));
    }
}

// ---------------- top-9 smallest of dnb per image (iterative extraction) ----------------
__global__ void k_top9(const float* __restrict__ dnb, int* __restrict__ support) {
    int b = blockIdx.x, tid = threadIdx.x;
    __shared__ int chosen[9];
    __shared__ u64 red[4];
    for (int p = 0; p < 9; ++p) {
        u64 best = ~0ull;
        for (int m = tid; m < M_; m += 256) {
            bool skip = false;
            for (int q = 0; q < p; ++q) if (chosen[q] == m) skip = true;
            if (skip) continue;
            float v = dnb[b * M_ + m];
            u64 pk = ((u64)ordf(v) << 32) | (u32)m;   // tie -> lowest m
            best = pk < best ? pk : best;
        }
        for (int msk = 1; msk < 64; msk <<= 1) {
            u64 o = __shfl_xor(best, msk, 64);
            best = o < best ? o : best;
        }
        int wave = tid >> 6, lane = tid & 63;
        if (lane == 0) red[wave] = best;
        __syncthreads();
        if (tid == 0) {
            u64 m = red[0];
            for (int w = 1; w < 4; ++w) m = red[w] < m ? red[w] : m;
            chosen[p] = (int)(u32)m;
            support[b * 9 + p] = chosen[p];
        }
        __syncthreads();
    }
}

// ---------------- d2 + softmax reweight -> pred_score ----------------
__global__ void k_final(const u16* __restrict__ Ah, const u16* __restrict__ Al,
                        const float* __restrict__ bank, const float* __restrict__ ynorm,
                        const float* __restrict__ xnorm, const int* __restrict__ mprow,
                        const int* __restrict__ support, const float* __restrict__ score,
                        float* __restrict__ out_score) {
    int b = blockIdx.x;
    int wave = threadIdx.x >> 6, lane = threadIdx.x & 63;
    __shared__ float d2s[9];
    int row = mprow[b];
    float xn = xnorm[row];
    for (int s = wave; s < 9; s += 4) {
        int sup = support[b * 9 + s];
        float acc = 0.f;
        for (int p = 0; p < 24; ++p) {
            int k = p * 64 + lane;
            float e = bf2f(Ah[(size_t)row * D_ + k]) + bf2f(Al[(size_t)row * D_ + k]);
            acc += e * bank[(size_t)sup * D_ + k];
        }
        for (int msk = 1; msk < 64; msk <<= 1) acc += __shfl_xor(acc, msk, 64);
        if (lane == 0) d2s[s] = sqrtf(fmaxf(xn - 2.f * acc + ynorm[sup], 0.f));
    }
    __syncthreads();
    if (threadIdx.x == 0) {
        float mx = d2s[0];
        for (int i = 1; i < 9; ++i) mx = fmaxf(mx, d2s[i]);
        float den = 0.f;
        for (int i = 0; i < 9; ++i) den += expf(d2s[i] - mx);
        float w = 1.f - expf(d2s[0] - mx) / den;
        out_score[b] = w * score[b];
    }
}

// ---------------- bilinear upsample 28->224 ----------------
__global__ void k_upsample(const float* __restrict__ ps, float* __restrict__ U) {
    int idx = blockIdx.x * 256 + threadIdx.x;
    if (idx >= B_ * IMG_ * IMG_) return;
    int x = idx % IMG_, y = (idx / IMG_) % IMG_, b = idx / (IMG_ * IMG_);
    float sx = x * 0.125f - 0.4375f, sy = y * 0.125f - 0.4375f;
    int ix = (int)floorf(sx), iy = (int)floorf(sy);
    float fx = sx - ix, fy = sy - iy;
    int x0 = min(max(ix, 0), 27), x1 = min(max(ix + 1, 0), 27);
    int y0 = min(max(iy, 0), 27), y1 = min(max(iy + 1, 0), 27);
    const float* p = ps + b * P_;
    U[idx] = (1.f - fy) * ((1.f - fx) * p[y0 * 28 + x0] + fx * p[y0 * 28 + x1])
           + fy * ((1.f - fx) * p[y1 * 28 + x0] + fx * p[y1 * 28 + x1]);
}

// ---------------- separable gaussian blur, reflect pad ----------------
__global__ void k_blurh(const float* __restrict__ U, float* __restrict__ T) {
    __shared__ float g[KS_];
    __shared__ float gs;
    int tid = threadIdx.x;
    if (tid < KS_) { float d = tid - 16.f; g[tid] = expf(-(d * d) / 32.0f); }
    __syncthreads();
    if (tid == 0) { float s = 0.f; for (int i = 0; i < KS_; ++i) s += g[i]; gs = 1.f / s; }
    __syncthreads();
    int idx = blockIdx.x * 256 + tid;
    if (idx >= B_ * IMG_ * IMG_) return;
    int x = idx % IMG_, rowbase = idx - x;
    float a = 0.f;
    for (int t = 0; t < KS_; ++t) {
        int xx = x + t - 16;
        xx = xx < 0 ? -xx : (xx > 223 ? 446 - xx : xx);
        a += g[t] * U[rowbase + xx];
    }
    T[idx] = a * gs;
}
__global__ void k_blurv(const float* __restrict__ T, float* __restrict__ out) {
    __shared__ float g[KS_];
    __shared__ float gs;
    int tid = threadIdx.x;
    if (tid < KS_) { float d = tid - 16.f; g[tid] = expf(-(d * d) / 32.0f); }
    __syncthreads();
    if (tid == 0) { float s = 0.f; for (int i = 0; i < KS_; ++i) s += g[i]; gs = 1.f / s; }
    __syncthreads();
    int idx = blockIdx.x * 256 + tid;
    if (idx >= B_ * IMG_ * IMG_) return;
    int x = idx % IMG_, y = (idx / IMG_) % IMG_, b = idx / (IMG_ * IMG_);
    float a = 0.f;
    for (int t = 0; t < KS_; ++t) {
        int yy = y + t - 16;
        yy = yy < 0 ? -yy : (yy > 223 ? 446 - yy : yy);
        a += g[t] * T[(b * IMG_ + yy) * IMG_ + x];
    }
    out[idx] = a * gs;
}

// ---------------- launch ----------------
extern "C" void kernel_launch(void* const* d_in, const int* in_sizes, int n_in,
                              void* d_out, int out_size, void* d_ws, size_t ws_size,
                              hipStream_t stream) {
    const float* feat1 = (const float*)d_in[0];
    const float* feat2 = (const float*)d_in[1];
    const float* bank  = (const float*)d_in[2];
    float* out = (float*)d_out;
    char* ws = (char*)d_ws;

    size_t o = 0;
    u16* Ah = (u16*)(ws + o); o += (size_t)N_ * D_ * 2;
    u16* Al = (u16*)(ws + o); o += (size_t)N_ * D_ * 2;
    size_t o_Bh = o;
    u16* Bh = (u16*)(ws + o); o += (size_t)MPAD_ * D_ * 2;
    u16* Bl = (u16*)(ws + o); o += (size_t)MPAD_ * D_ * 2;
    // part (GEMM-phase) aliases pooled2 (pre-GEMM phase)
    size_t o_part = o;
    u64* part = (u64*)(ws + o_part);
    float* pooled2 = (float*)(ws + o_part);
    size_t r1 = (size_t)MT_ * N_ * 8, r2 = (size_t)B_ * C2_ * 196 * 4;
    o += (r1 > r2 ? r1 : r2);
    float* xnorm = (float*)(ws + o); o += (size_t)N_ * 4;
    float* ynorm = (float*)(ws + o); o += (size_t)MPAD_ * 4;
    float* ps    = (float*)(ws + o); o += (size_t)N_ * 4;
    int*   loc   = (int*)(ws + o);   o += (size_t)N_ * 4;
    float* dnb   = (float*)(ws + o); o += (size_t)B_ * M_ * 4;
    int*   mprow = (int*)(ws + o);   o += 64;
    int*   nnidx = (int*)(ws + o);   o += 64;
    float* score = (float*)(ws + o); o += 64;
    int*   support = (int*)(ws + o); o += 9 * B_ * 4;
    // U/T alias the Bh/Bl region (dead after k_gemm)
    float* U = (float*)(ws + o_Bh);
    float* T = (float*)(ws + o_Bh + (size_t)B_ * IMG_ * IMG_ * 4);

    k_pool2<<<(B_ * C2_ * H2_ * H2_ + 255) / 256, 256, 0, stream>>>(feat2, pooled2);
    k_bank<<<MPAD_, 256, 0, stream>>>(bank, Bh, Bl, ynorm);
    k_embed<<<N_, 256, 0, stream>>>(feat1, pooled2, Ah, Al, xnorm);
    k_gemm<<<dim3(MT_, NT_), 256, 0, stream>>>(Ah, Al, Bh, Bl, ynorm, part);
    k_reduce<<<NT_, 128, 0, stream>>>(part, xnorm, ps, loc);
    k_argmax<<<B_, 256, 0, stream>>>(ps, loc, mprow, nnidx, score);
    k_dnb<<<dim3(235, B_), 256, 0, stream>>>(bank, ynorm, nnidx, dnb);
    k_top9<<<B_, 256, 0, stream>>>(dnb, support);
    k_final<<<B_, 256, 0, stream>>>(Ah, Al, bank, ynorm, xnorm, mprow, support, score,
                                    out + (size_t)B_ * IMG_ * IMG_);
    k_upsample<<<(B_ * IMG_ * IMG_ + 255) / 256, 256, 0, stream>>>(ps, U);
    k_blurh<<<(B_ * IMG_ * IMG_ + 255) / 256, 256, 0, stream>>>(U, T);
    k_blurv<<<(B_ * IMG_ * IMG_ + 255) / 256, 256, 0, stream>>>(T, out);
}

// Round 2
// 2804.492 us; speedup vs baseline: 1.0900x; 1.0900x over previous
//
#include <hip/hip_runtime.h>
#include <stdint.h>

// ---------------- problem constants ----------------
#define B_    16
#define C1_   512
#define C2_   1024
#define H2_   14
#define D_    1536
#define P_    784          // 28*28
#define N_    12544        // B_*P_
#define M_    15000
#define MPAD_ 15104        // 118*128
#define MT_   118          // m tiles of 128
#define NT_   98           // patch tiles of 128
#define IMG_  224
#define KS_   33

typedef unsigned short u16;
typedef unsigned int   u32;
typedef unsigned long long u64;

// ---------------- helpers ----------------
__device__ __forceinline__ u16 f2bf(float x) {
    u32 u = __float_as_uint(x);
    u = u + 0x7fffu + ((u >> 16) & 1u);   // RNE
    return (u16)(u >> 16);
}
__device__ __forceinline__ float bf2f(u16 h) {
    return __uint_as_float(((u32)h) << 16);
}
// monotone float->uint map (total order), and inverse
__device__ __forceinline__ u32 ordf(float f) {
    u32 u = __float_as_uint(f);
    return (u & 0x80000000u) ? ~u : (u | 0x80000000u);
}
__device__ __forceinline__ float unordf(u32 o) {
    u32 u = (o & 0x80000000u) ? (o ^ 0x80000000u) : ~o;
    return __uint_as_float(u);
}

// ---------------- avg-pool feat2 -> pooled2 [16,1024,14,14] ----------------
__global__ void k_pool2(const float* __restrict__ feat2, float* __restrict__ pooled2) {
    int idx = blockIdx.x * 256 + threadIdx.x;
    if (idx >= B_ * C2_ * H2_ * H2_) return;
    int x = idx % 14, y = (idx / 14) % 14, bc = idx / 196;
    const float* src = feat2 + (size_t)bc * 196;
    float s = 0.f;
    for (int dy = -1; dy <= 1; ++dy) {
        int yy = y + dy; if (yy < 0 || yy > 13) continue;
        for (int dx = -1; dx <= 1; ++dx) {
            int xx = x + dx; if (xx < 0 || xx > 13) continue;
            s += src[yy * 14 + xx];
        }
    }
    pooled2[idx] = s * (1.f / 9.f);
}

// ---------------- bank split (hi/lo bf16) + norms, with padding ----------------
__global__ void k_bank(const float* __restrict__ bank, u16* __restrict__ Bh,
                       u16* __restrict__ Bl, float* __restrict__ ynorm) {
    int m = blockIdx.x, tid = threadIdx.x;
    float nrm = 0.f;
    if (m < M_) {
        for (int p = 0; p < 6; ++p) {
            int c = p * 256 + tid;
            float v = bank[(size_t)m * D_ + c];
            u16 h = f2bf(v);
            Bh[(size_t)m * D_ + c] = h;
            Bl[(size_t)m * D_ + c] = f2bf(v - bf2f(h));
            nrm += v * v;
        }
    } else {
        for (int p = 0; p < 6; ++p) {
            int c = p * 256 + tid;
            Bh[(size_t)m * D_ + c] = 0; Bl[(size_t)m * D_ + c] = 0;
        }
    }
    __shared__ float red[4];
    for (int off = 32; off; off >>= 1) nrm += __shfl_down(nrm, off, 64);
    int wave = tid >> 6, lane = tid & 63;
    if (lane == 0) red[wave] = nrm;
    __syncthreads();
    if (tid == 0) {
        float t = red[0] + red[1] + red[2] + red[3];
        ynorm[m] = (m < M_) ? t : __uint_as_float(0x7f800000u);  // +inf pad
    }
}

// ---------------- embedding build: pool(feat1) ++ bilinear(pooled2), split, norms ----------------
__global__ void k_embed(const float* __restrict__ feat1, const float* __restrict__ pooled2,
                        u16* __restrict__ Ah, u16* __restrict__ Al, float* __restrict__ xnorm) {
    int n = blockIdx.x, tid = threadIdx.x;
    int b = n / P_, p = n % P_, y = p / 28, x = p % 28;
    float sy = y * 0.5f - 0.25f, sx = x * 0.5f - 0.25f;
    int iy = (int)floorf(sy), ix = (int)floorf(sx);
    float fy = sy - iy, fx = sx - ix;
    int y0 = min(max(iy, 0), 13), y1 = min(max(iy + 1, 0), 13);
    int x0 = min(max(ix, 0), 13), x1 = min(max(ix + 1, 0), 13);
    float nrm = 0.f;
    for (int pp = 0; pp < 6; ++pp) {
        int c = pp * 256 + tid;
        float v;
        if (c < C1_) {
            const float* src = feat1 + ((size_t)(b * C1_ + c)) * 784;
            float s = 0.f;
            for (int dy = -1; dy <= 1; ++dy) {
                int yy = y + dy; if (yy < 0 || yy > 27) continue;
                for (int dx = -1; dx <= 1; ++dx) {
                    int xx = x + dx; if (xx < 0 || xx > 27) continue;
                    s += src[yy * 28 + xx];
                }
            }
            v = s * (1.f / 9.f);
        } else {
            const float* sp = pooled2 + ((size_t)(b * C2_ + (c - C1_))) * 196;
            float v00 = sp[y0 * 14 + x0], v01 = sp[y0 * 14 + x1];
            float v10 = sp[y1 * 14 + x0], v11 = sp[y1 * 14 + x1];
            v = (1.f - fy) * ((1.f - fx) * v00 + fx * v01) + fy * ((1.f - fx) * v10 + fx * v11);
        }
        u16 h = f2bf(v);
        Ah[(size_t)n * D_ + c] = h;
        Al[(size_t)n * D_ + c] = f2bf(v - bf2f(h));
        nrm += v * v;
    }
    __shared__ float red[4];
    for (int off = 32; off; off >>= 1) nrm += __shfl_down(nrm, off, 64);
    int wave = tid >> 6, lane = tid & 63;
    if (lane == 0) red[wave] = nrm;
    __syncthreads();
    if (tid == 0) xnorm[n] = red[0] + red[1] + red[2] + red[3];
}

// ---------------- split-bf16 GEMM + fused min/argmin epilogue ----------------
// LDS layout: row-major 128 rows x 32 u16 (64 B = 4 chunks of 16 B), with XOR
// swizzle chunk_slot = chunk ^ ((row>>1)&3). Staging implements the swizzle on
// the SOURCE side (global_load_lds dest is fixed at base+lane*16); fragment
// reads apply the same swizzle. This spreads each 32-lane fragment read over
// all 32 banks (2 lanes / 4-bank group / quarter-phase) -> conflict-free.
typedef __bf16 bf16x8 __attribute__((ext_vector_type(8)));
typedef float  f32x16 __attribute__((ext_vector_type(16)));

__global__ __launch_bounds__(256)
void k_gemm(const u16* __restrict__ Ah, const u16* __restrict__ Al,
            const u16* __restrict__ Bh, const u16* __restrict__ Bl,
            const float* __restrict__ ynorm, u64* __restrict__ part) {
    __shared__ u16 sA[2][128 * 32];
    __shared__ u16 sB[2][128 * 32];
    __shared__ u64 smin[128][2];

    const int tid = threadIdx.x;
    const int lane = tid & 63, wave = tid >> 6;

    // grouped tile order: GM consecutive mt share the pt sweep -> B working set
    // of concurrent blocks ~6 MB (L2-resident) instead of all 93 MB
    const int GM = 8, nig = GM * NT_;
    const int grp = blockIdx.x / nig, rem = blockIdx.x - grp * nig;
    const int first = grp * GM;
    const int gsz = (MT_ - first) < GM ? (MT_ - first) : GM;
    const int mt = first + rem % gsz;
    const int pt = rem / gsz;
    const int p0 = pt * 128, m0 = mt * 128;

    f32x16 acc[2][2];
#pragma unroll
    for (int i = 0; i < 2; ++i)
#pragma unroll
        for (int j = 0; j < 2; ++j)
#pragma unroll
            for (int e = 0; e < 16; ++e) acc[i][j][e] = 0.f;

    const int srow = lane >> 2;                          // 0..15 within slab
    const int schunk = (lane & 3) ^ ((lane >> 3) & 3);   // source chunk (swizzled)
    const int scol = schunk * 8;                         // elements
    const int wr = (wave >> 1) * 64, wc = (wave & 1) * 64;
    const int rA = lane & 31;
    const int sw = (lane >> 1) & 3;                      // read-side swizzle term

    for (int kt = 0; kt < 48; ++kt) {
        const int k0 = kt * 32;
#pragma unroll
        for (int s = 0; s < 2; ++s) {
            const int slab = wave * 2 + s;
            const int row = slab * 16 + srow;
            const u16* ga = Ah + (size_t)(p0 + row) * D_ + k0 + scol;
            __builtin_amdgcn_global_load_lds((const __attribute__((address_space(1))) void*)ga,
                (__attribute__((address_space(3))) void*)&sA[0][slab * 512], 16, 0, 0);
            const u16* ga2 = Al + (size_t)(p0 + row) * D_ + k0 + scol;
            __builtin_amdgcn_global_load_lds((const __attribute__((address_space(1))) void*)ga2,
                (__attribute__((address_space(3))) void*)&sA[1][slab * 512], 16, 0, 0);
            const u16* gb = Bh + (size_t)(m0 + row) * D_ + k0 + scol;
            __builtin_amdgcn_global_load_lds((const __attribute__((address_space(1))) void*)gb,
                (__attribute__((address_space(3))) void*)&sB[0][slab * 512], 16, 0, 0);
            const u16* gb2 = Bl + (size_t)(m0 + row) * D_ + k0 + scol;
            __builtin_amdgcn_global_load_lds((const __attribute__((address_space(1))) void*)gb2,
                (__attribute__((address_space(3))) void*)&sB[1][slab * 512], 16, 0, 0);
        }
        __syncthreads();
#pragma unroll
        for (int ks = 0; ks < 2; ++ks) {
            // chunk this half-wave wants: ks*2 + (lane>>5); apply swizzle
            const int co = ((ks * 2 + (lane >> 5)) ^ sw) * 8;
            bf16x8 ah0 = *(const bf16x8*)&sA[0][(wr + rA) * 32 + co];
            bf16x8 ah1 = *(const bf16x8*)&sA[0][(wr + 32 + rA) * 32 + co];
            bf16x8 al0 = *(const bf16x8*)&sA[1][(wr + rA) * 32 + co];
            bf16x8 al1 = *(const bf16x8*)&sA[1][(wr + 32 + rA) * 32 + co];
            bf16x8 bh0 = *(const bf16x8*)&sB[0][(wc + rA) * 32 + co];
            bf16x8 bh1 = *(const bf16x8*)&sB[0][(wc + 32 + rA) * 32 + co];
            bf16x8 bl0 = *(const bf16x8*)&sB[1][(wc + rA) * 32 + co];
            bf16x8 bl1 = *(const bf16x8*)&sB[1][(wc + 32 + rA) * 32 + co];
            acc[0][0] = __builtin_amdgcn_mfma_f32_32x32x16_bf16(ah0, bh0, acc[0][0], 0, 0, 0);
            acc[0][1] = __builtin_amdgcn_mfma_f32_32x32x16_bf16(ah0, bh1, acc[0][1], 0, 0, 0);
            acc[1][0] = __builtin_amdgcn_mfma_f32_32x32x16_bf16(ah1, bh0, acc[1][0], 0, 0, 0);
            acc[1][1] = __builtin_amdgcn_mfma_f32_32x32x16_bf16(ah1, bh1, acc[1][1], 0, 0, 0);
            acc[0][0] = __builtin_amdgcn_mfma_f32_32x32x16_bf16(ah0, bl0, acc[0][0], 0, 0, 0);
            acc[0][1] = __builtin_amdgcn_mfma_f32_32x32x16_bf16(ah0, bl1, acc[0][1], 0, 0, 0);
            acc[1][0] = __builtin_amdgcn_mfma_f32_32x32x16_bf16(ah1, bl0, acc[1][0], 0, 0, 0);
            acc[1][1] = __builtin_amdgcn_mfma_f32_32x32x16_bf16(ah1, bl1, acc[1][1], 0, 0, 0);
            acc[0][0] = __builtin_amdgcn_mfma_f32_32x32x16_bf16(al0, bh0, acc[0][0], 0, 0, 0);
            acc[0][1] = __builtin_amdgcn_mfma_f32_32x32x16_bf16(al0, bh1, acc[0][1], 0, 0, 0);
            acc[1][0] = __builtin_amdgcn_mfma_f32_32x32x16_bf16(al1, bh0, acc[1][0], 0, 0, 0);
            acc[1][1] = __builtin_amdgcn_mfma_f32_32x32x16_bf16(al1, bh1, acc[1][1], 0, 0, 0);
        }
        __syncthreads();
    }

    // ---- epilogue: t = ynorm[col] - 2*acc ; min+argmin over this block's 128 cols ----
    const int wrB = wave >> 1, wcB = wave & 1;
    const int half = lane >> 5, c32 = lane & 31;
    float yn[2];
    yn[0] = ynorm[m0 + wcB * 64 + c32];
    yn[1] = ynorm[m0 + wcB * 64 + 32 + c32];
#pragma unroll
    for (int ti = 0; ti < 2; ++ti) {
#pragma unroll
        for (int reg = 0; reg < 16; ++reg) {
            const int rloc = wrB * 64 + ti * 32 + 4 * half + (reg & 3) + 8 * (reg >> 2);
            u64 best = ~0ull;
#pragma unroll
            for (int tj = 0; tj < 2; ++tj) {
                float v = yn[tj] - 2.0f * acc[ti][tj][reg];
                u32 col = (u32)(m0 + wcB * 64 + tj * 32 + c32);
                u64 pk = ((u64)ordf(v) << 32) | col;
                best = pk < best ? pk : best;
            }
#pragma unroll
            for (int msk = 1; msk < 32; msk <<= 1) {
                u64 o = __shfl_xor(best, msk, 64);
                best = o < best ? o : best;
            }
            if (c32 == 0) smin[rloc][wcB] = best;
        }
    }
    __syncthreads();
    if (tid < 128) {
        u64 a = smin[tid][0], b = smin[tid][1];
        part[(size_t)mt * N_ + p0 + tid] = a < b ? a : b;
    }
}

// ---------------- reduce partials over 118 m-tiles ----------------
__global__ void k_reduce(const u64* __restrict__ part, const float* __restrict__ xnorm,
                         float* __restrict__ ps, int* __restrict__ loc) {
    int n = blockIdx.x * 128 + threadIdx.x;
    u64 best = ~0ull;
    for (int t = 0; t < MT_; ++t) {
        u64 v = part[(size_t)t * N_ + n];
        best = v < best ? v : best;
    }
    float val = unordf((u32)(best >> 32));
    ps[n] = sqrtf(fmaxf(val + xnorm[n], 0.f));
    loc[n] = (int)(u32)best;
}

// ---------------- per-image argmax of patch scores ----------------
__global__ void k_argmax(const float* __restrict__ ps, const int* __restrict__ loc,
                         int* __restrict__ mprow, int* __restrict__ nnidx,
                         float* __restrict__ score) {
    int b = blockIdx.x, tid = threadIdx.x;
    u64 best = 0;
    for (int p = tid; p < P_; p += 256) {
        float v = ps[b * P_ + p];
        u64 pk = ((u64)ordf(v) << 32) | (u32)(~(u32)p);   // tie -> lowest p
        best = pk > best ? pk : best;
    }
    for (int msk = 1; msk < 64; msk <<= 1) {
        u64 o = __shfl_xor(best, msk, 64);
        best = o > best ? o : best;
    }
    __shared__ u64 red[4];
    int wave = tid >> 6, lane = tid & 63;
    if (lane == 0) red[wave] = best;
    __syncthreads();
    if (tid == 0) {
        u64 m = red[0];
        for (int w = 1; w < 4; ++w) m = red[w] > m ? red[w] : m;
        int p = (int)(~(u32)m);
        mprow[b] = b * P_ + p;
        nnidx[b] = loc[b * P_ + p];
        score[b] = unordf((u32)(m >> 32));
    }
}

// ---------------- d_nb: dist(bank[nn_index[b]], bank) exact fp32 ----------------
// loop order inverted vs R0: one wave per bank row, 16 image-accumulators ->
// bank read ONCE (92 MB) instead of 16x; nn rows (98 KB) stay hot in L1/L2.
__global__ void k_dnb(const float* __restrict__ bank, const float* __restrict__ ynorm,
                      const int* __restrict__ nnidx, float* __restrict__ dnb) {
    int wave = threadIdx.x >> 6, lane = threadIdx.x & 63;
    int m = blockIdx.x * 4 + wave;
    if (m >= M_) return;
    const float4* br = (const float4*)(bank + (size_t)m * D_);
    float acc[B_];
#pragma unroll
    for (int b = 0; b < B_; ++b) acc[b] = 0.f;
#pragma unroll
    for (int p = 0; p < 6; ++p) {
        float4 c = br[p * 64 + lane];
#pragma unroll
        for (int b = 0; b < B_; ++b) {
            const float4* nr = (const float4*)(bank + (size_t)nnidx[b] * D_);
            float4 a = nr[p * 64 + lane];
            acc[b] += a.x * c.x + a.y * c.y + a.z * c.z + a.w * c.w;
        }
    }
    float ym = ynorm[m];
    float keep = 0.f;
#pragma unroll
    for (int b = 0; b < B_; ++b) {
        float v = acc[b];
        for (int msk = 1; msk < 64; msk <<= 1) v += __shfl_xor(v, msk, 64);
        if (lane == b) keep = v;
    }
    if (lane < B_) {
        float ynn = ynorm[nnidx[lane]];
        dnb[lane * M_ + m] = sqrtf(fmaxf(ynn - 2.f * keep + ym, 0.f));
    }
}

// ---------------- top-9 smallest of dnb per image (iterative extraction) ----------------
__global__ void k_top9(const float* __restrict__ dnb, int* __restrict__ support) {
    int b = blockIdx.x, tid = threadIdx.x;
    __shared__ int chosen[9];
    __shared__ u64 red[4];
    for (int p = 0; p < 9; ++p) {
        u64 best = ~0ull;
        for (int m = tid; m < M_; m += 256) {
            bool skip = false;
            for (int q = 0; q < p; ++q) if (chosen[q] == m) skip = true;
            if (skip) continue;
            float v = dnb[b * M_ + m];
            u64 pk = ((u64)ordf(v) << 32) | (u32)m;   // tie -> lowest m
            best = pk < best ? pk : best;
        }
        for (int msk = 1; msk < 64; msk <<= 1) {
            u64 o = __shfl_xor(best, msk, 64);
            best = o < best ? o : best;
        }
        int wave = tid >> 6, lane = tid & 63;
        if (lane == 0) red[wave] = best;
        __syncthreads();
        if (tid == 0) {
            u64 m = red[0];
            for (int w = 1; w < 4; ++w) m = red[w] < m ? red[w] : m;
            chosen[p] = (int)(u32)m;
            support[b * 9 + p] = chosen[p];
        }
        __syncthreads();
    }
}

// ---------------- d2 + softmax reweight -> pred_score ----------------
__global__ void k_final(const u16* __restrict__ Ah, const u16* __restrict__ Al,
                        const float* __restrict__ bank, const float* __restrict__ ynorm,
                        const float* __restrict__ xnorm, const int* __restrict__ mprow,
                        const int* __restrict__ support, const float* __restrict__ score,
                        float* __restrict__ out_score) {
    int b = blockIdx.x;
    int wave = threadIdx.x >> 6, lane = threadIdx.x & 63;
    __shared__ float d2s[9];
    int row = mprow[b];
    float xn = xnorm[row];
    for (int s = wave; s < 9; s += 4) {
        int sup = support[b * 9 + s];
        float acc = 0.f;
        for (int p = 0; p < 24; ++p) {
            int k = p * 64 + lane;
            float e = bf2f(Ah[(size_t)row * D_ + k]) + bf2f(Al[(size_t)row * D_ + k]);
            acc += e * bank[(size_t)sup * D_ + k];
        }
        for (int msk = 1; msk < 64; msk <<= 1) acc += __shfl_xor(acc, msk, 64);
        if (lane == 0) d2s[s] = sqrtf(fmaxf(xn - 2.f * acc + ynorm[sup], 0.f));
    }
    __syncthreads();
    if (threadIdx.x == 0) {
        float mx = d2s[0];
        for (int i = 1; i < 9; ++i) mx = fmaxf(mx, d2s[i]);
        float den = 0.f;
        for (int i = 0; i < 9; ++i) den += expf(d2s[i] - mx);
        float w = 1.f - expf(d2s[0] - mx) / den;
        out_score[b] = w * score[b];
    }
}

// ---------------- bilinear upsample 28->224 ----------------
__global__ void k_upsample(const float* __restrict__ ps, float* __restrict__ U) {
    int idx = blockIdx.x * 256 + threadIdx.x;
    if (idx >= B_ * IMG_ * IMG_) return;
    int x = idx % IMG_, y = (idx / IMG_) % IMG_, b = idx / (IMG_ * IMG_);
    float sx = x * 0.125f - 0.4375f, sy = y * 0.125f - 0.4375f;
    int ix = (int)floorf(sx), iy = (int)floorf(sy);
    float fx = sx - ix, fy = sy - iy;
    int x0 = min(max(ix, 0), 27), x1 = min(max(ix + 1, 0), 27);
    int y0 = min(max(iy, 0), 27), y1 = min(max(iy + 1, 0), 27);
    const float* p = ps + b * P_;
    U[idx] = (1.f - fy) * ((1.f - fx) * p[y0 * 28 + x0] + fx * p[y0 * 28 + x1])
           + fy * ((1.f - fx) * p[y1 * 28 + x0] + fx * p[y1 * 28 + x1]);
}

// ---------------- separable gaussian blur, reflect pad ----------------
__global__ void k_blurh(const float* __restrict__ U, float* __restrict__ T) {
    __shared__ float g[KS_];
    __shared__ float gs;
    int tid = threadIdx.x;
    if (tid < KS_) { float d = tid - 16.f; g[tid] = expf(-(d * d) / 32.0f); }
    __syncthreads();
    if (tid == 0) { float s = 0.f; for (int i = 0; i < KS_; ++i) s += g[i]; gs = 1.f / s; }
    __syncthreads();
    int idx = blockIdx.x * 256 + tid;
    if (idx >= B_ * IMG_ * IMG_) return;
    int x = idx % IMG_, rowbase = idx - x;
    float a = 0.f;
    for (int t = 0; t < KS_; ++t) {
        int xx = x + t - 16;
        xx = xx < 0 ? -xx : (xx > 223 ? 446 - xx : xx);
        a += g[t] * U[rowbase + xx];
    }
    T[idx] = a * gs;
}
__global__ void k_blurv(const float* __restrict__ T, float* __restrict__ out) {
    __shared__ float g[KS_];
    __shared__ float gs;
    int tid = threadIdx.x;
    if (tid < KS_) { float d = tid - 16.f; g[tid] = expf(-(d * d) / 32.0f); }
    __syncthreads();
    if (tid == 0) { float s = 0.f; for (int i = 0; i < KS_; ++i) s += g[i]; gs = 1.f / s; }
    __syncthreads();
    int idx = blockIdx.x * 256 + tid;
    if (idx >= B_ * IMG_ * IMG_) return;
    int x = idx % IMG_, y = (idx / IMG_) % IMG_, b = idx / (IMG_ * IMG_);
    float a = 0.f;
    for (int t = 0; t < KS_; ++t) {
        int yy = y + t - 16;
        yy = yy < 0 ? -yy : (yy > 223 ? 446 - yy : yy);
        a += g[t] * T[(b * IMG_ + yy) * IMG_ + x];
    }
    out[idx] = a * gs;
}

// ---------------- launch ----------------
extern "C" void kernel_launch(void* const* d_in, const int* in_sizes, int n_in,
                              void* d_out, int out_size, void* d_ws, size_t ws_size,
                              hipStream_t stream) {
    const float* feat1 = (const float*)d_in[0];
    const float* feat2 = (const float*)d_in[1];
    const float* bank  = (const float*)d_in[2];
    float* out = (float*)d_out;
    char* ws = (char*)d_ws;

    size_t o = 0;
    u16* Ah = (u16*)(ws + o); o += (size_t)N_ * D_ * 2;
    u16* Al = (u16*)(ws + o); o += (size_t)N_ * D_ * 2;
    size_t o_Bh = o;
    u16* Bh = (u16*)(ws + o); o += (size_t)MPAD_ * D_ * 2;
    u16* Bl = (u16*)(ws + o); o += (size_t)MPAD_ * D_ * 2;
    // part (GEMM-phase) aliases pooled2 (pre-GEMM phase)
    size_t o_part = o;
    u64* part = (u64*)(ws + o_part);
    float* pooled2 = (float*)(ws + o_part);
    size_t r1 = (size_t)MT_ * N_ * 8, r2 = (size_t)B_ * C2_ * 196 * 4;
    o += (r1 > r2 ? r1 : r2);
    float* xnorm = (float*)(ws + o); o += (size_t)N_ * 4;
    float* ynorm = (float*)(ws + o); o += (size_t)MPAD_ * 4;
    float* ps    = (float*)(ws + o); o += (size_t)N_ * 4;
    int*   loc   = (int*)(ws + o);   o += (size_t)N_ * 4;
    float* dnb   = (float*)(ws + o); o += (size_t)B_ * M_ * 4;
    int*   mprow = (int*)(ws + o);   o += 64;
    int*   nnidx = (int*)(ws + o);   o += 64;
    float* score = (float*)(ws + o); o += 64;
    int*   support = (int*)(ws + o); o += 9 * B_ * 4;
    // U/T alias the Bh/Bl region (dead after k_gemm)
    float* U = (float*)(ws + o_Bh);
    float* T = (float*)(ws + o_Bh + (size_t)B_ * IMG_ * IMG_ * 4);

    k_pool2<<<(B_ * C2_ * H2_ * H2_ + 255) / 256, 256, 0, stream>>>(feat2, pooled2);
    k_bank<<<MPAD_, 256, 0, stream>>>(bank, Bh, Bl, ynorm);
    k_embed<<<N_, 256, 0, stream>>>(feat1, pooled2, Ah, Al, xnorm);
    k_gemm<<<MT_ * NT_, 256, 0, stream>>>(Ah, Al, Bh, Bl, ynorm, part);
    k_reduce<<<NT_, 128, 0, stream>>>(part, xnorm, ps, loc);
    k_argmax<<<B_, 256, 0, stream>>>(ps, loc, mprow, nnidx, score);
    k_dnb<<<(M_ + 3) / 4, 256, 0, stream>>>(bank, ynorm, nnidx, dnb);
    k_top9<<<B_, 256, 0, stream>>>(dnb, support);
    k_final<<<B_, 256, 0, stream>>>(Ah, Al, bank, ynorm, xnorm, mprow, support, score,
                                    out + (size_t)B_ * IMG_ * IMG_);
    k_upsample<<<(B_ * IMG_ * IMG_ + 255) / 256, 256, 0, stream>>>(ps, U);
    k_blurh<<<(B_ * IMG_ * IMG_ + 255) / 256, 256, 0, stream>>>(U, T);
    k_blurv<<<(B_ * IMG_ * IMG_ + 255) / 256, 256, 0, stream>>>(T, out);
}

// Round 3
// 2044.424 us; speedup vs baseline: 1.4952x; 1.3718x over previous
//
#include <hip/hip_runtime.h>
#include <stdint.h>

// ---------------- problem constants ----------------
#define B_    16
#define C1_   512
#define C2_   1024
#define H2_   14
#define D_    1536
#define P_    784          // 28*28
#define N_    12544        // B_*P_
#define M_    15000
#define MPAD_ 15104        // 118*128
#define MT_   118          // m tiles of 128
#define NT_   98           // patch tiles of 128
#define IMG_  224
#define KS_   33

typedef unsigned short u16;
typedef unsigned int   u32;
typedef unsigned long long u64;

// ---------------- helpers ----------------
__device__ __forceinline__ u16 f2bf(float x) {
    u32 u = __float_as_uint(x);
    u = u + 0x7fffu + ((u >> 16) & 1u);   // RNE
    return (u16)(u >> 16);
}
__device__ __forceinline__ float bf2f(u16 h) {
    return __uint_as_float(((u32)h) << 16);
}
__device__ __forceinline__ u32 ordf(float f) {
    u32 u = __float_as_uint(f);
    return (u & 0x80000000u) ? ~u : (u | 0x80000000u);
}
__device__ __forceinline__ float unordf(u32 o) {
    u32 u = (o & 0x80000000u) ? (o ^ 0x80000000u) : ~o;
    return __uint_as_float(u);
}

// ---------------- avg-pool feat2 -> pooled2 [16,1024,14,14] ----------------
__global__ void k_pool2(const float* __restrict__ feat2, float* __restrict__ pooled2) {
    int idx = blockIdx.x * 256 + threadIdx.x;
    if (idx >= B_ * C2_ * H2_ * H2_) return;
    int x = idx % 14, y = (idx / 14) % 14, bc = idx / 196;
    const float* src = feat2 + (size_t)bc * 196;
    float s = 0.f;
    for (int dy = -1; dy <= 1; ++dy) {
        int yy = y + dy; if (yy < 0 || yy > 13) continue;
        for (int dx = -1; dx <= 1; ++dx) {
            int xx = x + dx; if (xx < 0 || xx > 13) continue;
            s += src[yy * 14 + xx];
        }
    }
    pooled2[idx] = s * (1.f / 9.f);
}

// ---------------- bank split (hi/lo bf16) + norms, with padding ----------------
__global__ void k_bank(const float* __restrict__ bank, u16* __restrict__ Bh,
                       u16* __restrict__ Bl, float* __restrict__ ynorm) {
    int m = blockIdx.x, tid = threadIdx.x;
    float nrm = 0.f;
    if (m < M_) {
        for (int p = 0; p < 6; ++p) {
            int c = p * 256 + tid;
            float v = bank[(size_t)m * D_ + c];
            u16 h = f2bf(v);
            Bh[(size_t)m * D_ + c] = h;
            Bl[(size_t)m * D_ + c] = f2bf(v - bf2f(h));
            nrm += v * v;
        }
    } else {
        for (int p = 0; p < 6; ++p) {
            int c = p * 256 + tid;
            Bh[(size_t)m * D_ + c] = 0; Bl[(size_t)m * D_ + c] = 0;
        }
    }
    __shared__ float red[4];
    for (int off = 32; off; off >>= 1) nrm += __shfl_down(nrm, off, 64);
    int wave = tid >> 6, lane = tid & 63;
    if (lane == 0) red[wave] = nrm;
    __syncthreads();
    if (tid == 0) {
        float t = red[0] + red[1] + red[2] + red[3];
        ynorm[m] = (m < M_) ? t : __uint_as_float(0x7f800000u);  // +inf pad
    }
}

// ---------------- embedding build, row-block version ----------------
// block = (image b, patch-row y). Stages 3 feat1 rows x 64ch into LDS so each
// feat1 line is read once per row-block (was: once per patch = 9x traffic).
__global__ __launch_bounds__(256)
void k_embed(const float* __restrict__ feat1, const float* __restrict__ pooled2,
             u16* __restrict__ Ah, u16* __restrict__ Al, float* __restrict__ xnorm) {
    __shared__ float sF[3 * 64 * 29];   // [r][c][x] padded to 29
    __shared__ float xn[28];
    const int tid = threadIdx.x, lane = tid & 63, wave = tid >> 6;
    const int b = blockIdx.x / 28, y = blockIdx.x % 28;
    const int brow = b * P_ + y * 28;
    if (tid < 28) xn[tid] = 0.f;

    // bilinear params for the 14->28 upsample (row fixed per block)
    float sy = y * 0.5f - 0.25f;
    int iy = (int)floorf(sy);
    float fy = sy - iy;
    int y0 = min(max(iy, 0), 13), y1 = min(max(iy + 1, 0), 13);
    __syncthreads();

    // ---- feat1 channels (512) in 8 chunks of 64 ----
    for (int cc = 0; cc < 8; ++cc) {
        for (int j = tid; j < 3 * 64 * 28; j += 256) {
            int x = j % 28, c = (j / 28) % 64, r = j / (28 * 64);
            int yy = y - 1 + r;
            float v = 0.f;
            if (yy >= 0 && yy < 28)
                v = feat1[((size_t)(b * C1_ + cc * 64 + c)) * 784 + yy * 28 + x];
            sF[(r * 64 + c) * 29 + x] = v;
        }
        __syncthreads();
        for (int it = 0; it < 7; ++it) {
            int x = it * 4 + wave, c = lane;
            float s = 0.f;
#pragma unroll
            for (int r = 0; r < 3; ++r) {
                int base = (r * 64 + c) * 29;
                if (x > 0) s += sF[base + x - 1];
                s += sF[base + x];
                if (x < 27) s += sF[base + x + 1];
            }
            float v = s * (1.f / 9.f);
            int col = cc * 64 + c;
            size_t off = (size_t)(brow + x) * D_ + col;
            u16 h = f2bf(v);
            Ah[off] = h; Al[off] = f2bf(v - bf2f(h));
            float vv = v * v;
            for (int m = 1; m < 64; m <<= 1) vv += __shfl_xor(vv, m, 64);
            if (lane == 0) atomicAdd(&xn[x], vv);
        }
        __syncthreads();
    }

    // ---- pooled2 channels (1024) in 16 chunks of 64, bilinear ----
    for (int cc = 0; cc < 16; ++cc) {
        for (int it = 0; it < 7; ++it) {
            int x = it * 4 + wave, c = lane;
            const float* sp = pooled2 + ((size_t)(b * C2_ + cc * 64 + c)) * 196;
            float sx = x * 0.5f - 0.25f;
            int ix = (int)floorf(sx);
            float fx = sx - ix;
            int x0 = min(max(ix, 0), 13), x1 = min(max(ix + 1, 0), 13);
            float v = (1.f - fy) * ((1.f - fx) * sp[y0 * 14 + x0] + fx * sp[y0 * 14 + x1])
                    + fy * ((1.f - fx) * sp[y1 * 14 + x0] + fx * sp[y1 * 14 + x1]);
            int col = C1_ + cc * 64 + c;
            size_t off = (size_t)(brow + x) * D_ + col;
            u16 h = f2bf(v);
            Ah[off] = h; Al[off] = f2bf(v - bf2f(h));
            float vv = v * v;
            for (int m = 1; m < 64; m <<= 1) vv += __shfl_xor(vv, m, 64);
            if (lane == 0) atomicAdd(&xn[x], vv);
        }
    }
    __syncthreads();
    if (tid < 28) xnorm[brow + tid] = xn[tid];
}

// ---------------- phase-1: bf16-only GEMM, value-min epilogue ----------------
// A (patches) staged in LDS, BK=64, XOR-swizzled (row=128B=32 banks exactly;
// slot = chunk ^ (row&7) -> 32-lane fragment read covers all 8 granules).
// B fragments loaded DIRECTLY from global (L1/L2-served) -> LDS pipe halved,
// barrier only covers A staging.
typedef __bf16 bf16x8 __attribute__((ext_vector_type(8)));
typedef float  f32x16 __attribute__((ext_vector_type(16)));

__global__ __launch_bounds__(256)
void k_gemm1(const u16* __restrict__ Ah, const u16* __restrict__ Bh,
             const float* __restrict__ ynorm, float* __restrict__ partf) {
    __shared__ u16 sA[128 * 64];       // 16 KB
    __shared__ float smin[128][2];

    const int tid = threadIdx.x, lane = tid & 63, wave = tid >> 6;
    // grouped tile order for B locality
    const int GM = 8, nig = GM * NT_;
    const int grp = blockIdx.x / nig, rem = blockIdx.x - grp * nig;
    const int first = grp * GM;
    const int gsz = (MT_ - first) < GM ? (MT_ - first) : GM;
    const int mt = first + rem % gsz;
    const int pt = rem / gsz;
    const int p0 = pt * 128, m0 = mt * 128;

    f32x16 acc[2][2];
#pragma unroll
    for (int i = 0; i < 2; ++i)
#pragma unroll
        for (int j = 0; j < 2; ++j)
#pragma unroll
            for (int e = 0; e < 16; ++e) acc[i][j][e] = 0.f;

    const int srow = lane >> 3;              // 0..7 row within 8-row slab
    const int schunk = (lane & 7) ^ srow;    // source chunk (swizzle on source side)
    const int wr = (wave >> 1) * 64, wc = (wave & 1) * 64;
    const int rA = lane & 31, kh = lane >> 5;
    const int rsw = rA & 7;                  // read-side swizzle key

    const u16* gB0 = Bh + (size_t)(m0 + wc + rA) * D_;
    const u16* gB1 = Bh + (size_t)(m0 + wc + 32 + rA) * D_;

    for (int kt = 0; kt < 24; ++kt) {
        const int k0 = kt * 64;
#pragma unroll
        for (int s = 0; s < 4; ++s) {
            const int slab = wave * 4 + s;
            const int row = slab * 8 + srow;
            const u16* ga = Ah + (size_t)(p0 + row) * D_ + k0 + schunk * 8;
            __builtin_amdgcn_global_load_lds((const __attribute__((address_space(1))) void*)ga,
                (__attribute__((address_space(3))) void*)&sA[slab * 512], 16, 0, 0);
        }
        __syncthreads();
#pragma unroll
        for (int ks = 0; ks < 4; ++ks) {
            const int kc = ks * 2 + kh;                 // chunk 0..7
            const int slot = (kc ^ rsw) * 8;
            bf16x8 a0 = *(const bf16x8*)&sA[(wr + rA) * 64 + slot];
            bf16x8 a1 = *(const bf16x8*)&sA[(wr + 32 + rA) * 64 + slot];
            bf16x8 b0 = *(const bf16x8*)(gB0 + k0 + ks * 16 + kh * 8);
            bf16x8 b1 = *(const bf16x8*)(gB1 + k0 + ks * 16 + kh * 8);
            acc[0][0] = __builtin_amdgcn_mfma_f32_32x32x16_bf16(a0, b0, acc[0][0], 0, 0, 0);
            acc[0][1] = __builtin_amdgcn_mfma_f32_32x32x16_bf16(a0, b1, acc[0][1], 0, 0, 0);
            acc[1][0] = __builtin_amdgcn_mfma_f32_32x32x16_bf16(a1, b0, acc[1][0], 0, 0, 0);
            acc[1][1] = __builtin_amdgcn_mfma_f32_32x32x16_bf16(a1, b1, acc[1][1], 0, 0, 0);
        }
        __syncthreads();
    }

    // epilogue: val = ynorm[col] - 2*acc ; min over this block's 128 cols
    const int half = lane >> 5, c32 = lane & 31;
    float yn0 = ynorm[m0 + wc + c32];
    float yn1 = ynorm[m0 + wc + 32 + c32];
#pragma unroll
    for (int ti = 0; ti < 2; ++ti) {
#pragma unroll
        for (int reg = 0; reg < 16; ++reg) {
            const int rloc = wr + ti * 32 + 4 * half + (reg & 3) + 8 * (reg >> 2);
            float v0 = yn0 - 2.0f * acc[ti][0][reg];
            float v1 = yn1 - 2.0f * acc[ti][1][reg];
            float v = fminf(v0, v1);
#pragma unroll
            for (int msk = 1; msk < 32; msk <<= 1)
                v = fminf(v, __shfl_xor(v, msk, 64));
            if (c32 == 0) smin[rloc][wave & 1] = v;
        }
    }
    __syncthreads();
    if (tid < 128)
        partf[(size_t)mt * N_ + p0 + tid] = fminf(smin[tid][0], smin[tid][1]);
}

// ---------------- reduce partial mins -> approx patch scores ----------------
__global__ void k_reduce(const float* __restrict__ partf, const float* __restrict__ xnorm,
                         float* __restrict__ ps) {
    int n = blockIdx.x * 128 + threadIdx.x;
    float best = __uint_as_float(0x7f800000u);
    for (int t = 0; t < MT_; ++t)
        best = fminf(best, partf[(size_t)t * N_ + n]);
    ps[n] = sqrtf(fmaxf(best + xnorm[n], 0.f));
}

// ---------------- per-image approx top-8 patches (candidates) ----------------
__global__ void k_cand(const float* __restrict__ ps, int* __restrict__ candrow) {
    int b = blockIdx.x, tid = threadIdx.x;
    __shared__ int chosen[8];
    __shared__ u64 red[4];
    for (int j = 0; j < 8; ++j) {
        u64 best = 0;
        for (int p = tid; p < P_; p += 256) {
            bool skip = false;
            for (int q = 0; q < j; ++q) if (chosen[q] == p) skip = true;
            if (skip) continue;
            u64 pk = ((u64)ordf(ps[b * P_ + p]) << 32) | (u32)(~(u32)p);
            best = pk > best ? pk : best;
        }
        for (int msk = 1; msk < 64; msk <<= 1) {
            u64 o = __shfl_xor(best, msk, 64);
            best = o > best ? o : best;
        }
        int wave = tid >> 6, lane = tid & 63;
        if (lane == 0) red[wave] = best;
        __syncthreads();
        if (tid == 0) {
            u64 m = red[0];
            for (int w = 1; w < 4; ++w) m = red[w] > m ? red[w] : m;
            int p = (int)(~(u32)m);
            chosen[j] = p;
            candrow[b * 8 + j] = b * P_ + p;
        }
        __syncthreads();
    }
}

// ---------------- phase-2: exact 3-term split GEMM over 128 candidate rows ----
__global__ __launch_bounds__(256)
void k_gexact(const u16* __restrict__ Ah, const u16* __restrict__ Al,
              const u16* __restrict__ Bh, const u16* __restrict__ Bl,
              const float* __restrict__ ynorm, const int* __restrict__ candrow,
              u64* __restrict__ parte) {
    __shared__ u16 sA[2][128 * 32];
    __shared__ u16 sB[2][128 * 32];
    __shared__ u64 smin[128][2];
    __shared__ int scand[128];

    const int tid = threadIdx.x;
    const int lane = tid & 63, wave = tid >> 6;
    const int mt = blockIdx.x;
    const int m0 = mt * 128;
    if (tid < 128) scand[tid] = candrow[tid];

    f32x16 acc[2][2];
#pragma unroll
    for (int i = 0; i < 2; ++i)
#pragma unroll
        for (int j = 0; j < 2; ++j)
#pragma unroll
            for (int e = 0; e < 16; ++e) acc[i][j][e] = 0.f;

    const int srow = lane >> 2;
    const int scol = ((lane & 3) ^ ((lane >> 3) & 3)) * 8;
    const int wr = (wave >> 1) * 64, wc = (wave & 1) * 64;
    const int rA = lane & 31;
    const int sw = (lane >> 1) & 3;
    __syncthreads();

    for (int kt = 0; kt < 48; ++kt) {
        const int k0 = kt * 32;
#pragma unroll
        for (int s = 0; s < 2; ++s) {
            const int slab = wave * 2 + s;
            const int row = slab * 16 + srow;
            const int grow = scand[row];
            const u16* ga = Ah + (size_t)grow * D_ + k0 + scol;
            __builtin_amdgcn_global_load_lds((const __attribute__((address_space(1))) void*)ga,
                (__attribute__((address_space(3))) void*)&sA[0][slab * 512], 16, 0, 0);
            const u16* ga2 = Al + (size_t)grow * D_ + k0 + scol;
            __builtin_amdgcn_global_load_lds((const __attribute__((address_space(1))) void*)ga2,
                (__attribute__((address_space(3))) void*)&sA[1][slab * 512], 16, 0, 0);
            const u16* gb = Bh + (size_t)(m0 + row) * D_ + k0 + scol;
            __builtin_amdgcn_global_load_lds((const __attribute__((address_space(1))) void*)gb,
                (__attribute__((address_space(3))) void*)&sB[0][slab * 512], 16, 0, 0);
            const u16* gb2 = Bl + (size_t)(m0 + row) * D_ + k0 + scol;
            __builtin_amdgcn_global_load_lds((const __attribute__((address_space(1))) void*)gb2,
                (__attribute__((address_space(3))) void*)&sB[1][slab * 512], 16, 0, 0);
        }
        __syncthreads();
#pragma unroll
        for (int ks = 0; ks < 2; ++ks) {
            const int co = ((ks * 2 + (lane >> 5)) ^ sw) * 8;
            bf16x8 ah0 = *(const bf16x8*)&sA[0][(wr + rA) * 32 + co];
            bf16x8 ah1 = *(const bf16x8*)&sA[0][(wr + 32 + rA) * 32 + co];
            bf16x8 al0 = *(const bf16x8*)&sA[1][(wr + rA) * 32 + co];
            bf16x8 al1 = *(const bf16x8*)&sA[1][(wr + 32 + rA) * 32 + co];
            bf16x8 bh0 = *(const bf16x8*)&sB[0][(wc + rA) * 32 + co];
            bf16x8 bh1 = *(const bf16x8*)&sB[0][(wc + 32 + rA) * 32 + co];
            bf16x8 bl0 = *(const bf16x8*)&sB[1][(wc + rA) * 32 + co];
            bf16x8 bl1 = *(const bf16x8*)&sB[1][(wc + 32 + rA) * 32 + co];
            acc[0][0] = __builtin_amdgcn_mfma_f32_32x32x16_bf16(ah0, bh0, acc[0][0], 0, 0, 0);
            acc[0][1] = __builtin_amdgcn_mfma_f32_32x32x16_bf16(ah0, bh1, acc[0][1], 0, 0, 0);
            acc[1][0] = __builtin_amdgcn_mfma_f32_32x32x16_bf16(ah1, bh0, acc[1][0], 0, 0, 0);
            acc[1][1] = __builtin_amdgcn_mfma_f32_32x32x16_bf16(ah1, bh1, acc[1][1], 0, 0, 0);
            acc[0][0] = __builtin_amdgcn_mfma_f32_32x32x16_bf16(ah0, bl0, acc[0][0], 0, 0, 0);
            acc[0][1] = __builtin_amdgcn_mfma_f32_32x32x16_bf16(ah0, bl1, acc[0][1], 0, 0, 0);
            acc[1][0] = __builtin_amdgcn_mfma_f32_32x32x16_bf16(ah1, bl0, acc[1][0], 0, 0, 0);
            acc[1][1] = __builtin_amdgcn_mfma_f32_32x32x16_bf16(ah1, bl1, acc[1][1], 0, 0, 0);
            acc[0][0] = __builtin_amdgcn_mfma_f32_32x32x16_bf16(al0, bh0, acc[0][0], 0, 0, 0);
            acc[0][1] = __builtin_amdgcn_mfma_f32_32x32x16_bf16(al0, bh1, acc[0][1], 0, 0, 0);
            acc[1][0] = __builtin_amdgcn_mfma_f32_32x32x16_bf16(al1, bh0, acc[1][0], 0, 0, 0);
            acc[1][1] = __builtin_amdgcn_mfma_f32_32x32x16_bf16(al1, bh1, acc[1][1], 0, 0, 0);
        }
        __syncthreads();
    }

    const int wrB = wave >> 1, wcB = wave & 1;
    const int half = lane >> 5, c32 = lane & 31;
    float yn[2];
    yn[0] = ynorm[m0 + wcB * 64 + c32];
    yn[1] = ynorm[m0 + wcB * 64 + 32 + c32];
#pragma unroll
    for (int ti = 0; ti < 2; ++ti) {
#pragma unroll
        for (int reg = 0; reg < 16; ++reg) {
            const int rloc = wrB * 64 + ti * 32 + 4 * half + (reg & 3) + 8 * (reg >> 2);
            u64 best = ~0ull;
#pragma unroll
            for (int tj = 0; tj < 2; ++tj) {
                float v = yn[tj] - 2.0f * acc[ti][tj][reg];
                u32 col = (u32)(m0 + wcB * 64 + tj * 32 + c32);
                u64 pk = ((u64)ordf(v) << 32) | col;
                best = pk < best ? pk : best;
            }
#pragma unroll
            for (int msk = 1; msk < 32; msk <<= 1) {
                u64 o = __shfl_xor(best, msk, 64);
                best = o < best ? o : best;
            }
            if (c32 == 0) smin[rloc][wcB] = best;
        }
    }
    __syncthreads();
    if (tid < 128) {
        u64 a = smin[tid][0], b = smin[tid][1];
        parte[(size_t)mt * 128 + tid] = a < b ? a : b;
    }
}

// ---------------- pick exact winner per image ----------------
__global__ void k_pick(const u64* __restrict__ parte, const float* __restrict__ xnorm,
                       const int* __restrict__ candrow, int* __restrict__ mprow,
                       int* __restrict__ nnidx, float* __restrict__ score) {
    __shared__ float sps[128];
    __shared__ int sloc[128];
    int i = threadIdx.x;   // 0..127
    u64 best = ~0ull;
    for (int t = 0; t < MT_; ++t) {
        u64 v = parte[(size_t)t * 128 + i];
        best = v < best ? v : best;
    }
    float val = unordf((u32)(best >> 32)) + xnorm[candrow[i]];
    sps[i] = sqrtf(fmaxf(val, 0.f));
    sloc[i] = (int)(u32)best;
    __syncthreads();
    if (i < B_) {
        float bs = -1.f; int bj = 0; int brw = 1 << 30;
        for (int j = 0; j < 8; ++j) {
            int idx = i * 8 + j;
            float v = sps[idx];
            int row = candrow[idx];
            if (v > bs || (v == bs && row < brw)) { bs = v; bj = idx; brw = row; }
        }
        mprow[i] = brw;
        nnidx[i] = sloc[bj];
        score[i] = bs;
    }
}

// ---------------- d_nb: dist(bank[nn_index[b]], bank) exact fp32 ----------------
__global__ void k_dnb(const float* __restrict__ bank, const float* __restrict__ ynorm,
                      const int* __restrict__ nnidx, float* __restrict__ dnb) {
    int wave = threadIdx.x >> 6, lane = threadIdx.x & 63;
    int m = blockIdx.x * 4 + wave;
    if (m >= M_) return;
    const float4* br = (const float4*)(bank + (size_t)m * D_);
    float acc[B_];
#pragma unroll
    for (int b = 0; b < B_; ++b) acc[b] = 0.f;
#pragma unroll
    for (int p = 0; p < 6; ++p) {
        float4 c = br[p * 64 + lane];
#pragma unroll
        for (int b = 0; b < B_; ++b) {
            const float4* nr = (const float4*)(bank + (size_t)nnidx[b] * D_);
            float4 a = nr[p * 64 + lane];
            acc[b] += a.x * c.x + a.y * c.y + a.z * c.z + a.w * c.w;
        }
    }
    float ym = ynorm[m];
    float keep = 0.f;
#pragma unroll
    for (int b = 0; b < B_; ++b) {
        float v = acc[b];
        for (int msk = 1; msk < 64; msk <<= 1) v += __shfl_xor(v, msk, 64);
        if (lane == b) keep = v;
    }
    if (lane < B_) {
        float ynn = ynorm[nnidx[lane]];
        dnb[lane * M_ + m] = sqrtf(fmaxf(ynn - 2.f * keep + ym, 0.f));
    }
}

// ---------------- top-9 smallest of dnb per image ----------------
__global__ void k_top9(const float* __restrict__ dnb, int* __restrict__ support) {
    int b = blockIdx.x, tid = threadIdx.x;
    __shared__ int chosen[9];
    __shared__ u64 red[4];
    for (int p = 0; p < 9; ++p) {
        u64 best = ~0ull;
        for (int m = tid; m < M_; m += 256) {
            bool skip = false;
            for (int q = 0; q < p; ++q) if (chosen[q] == m) skip = true;
            if (skip) continue;
            float v = dnb[b * M_ + m];
            u64 pk = ((u64)ordf(v) << 32) | (u32)m;
            best = pk < best ? pk : best;
        }
        for (int msk = 1; msk < 64; msk <<= 1) {
            u64 o = __shfl_xor(best, msk, 64);
            best = o < best ? o : best;
        }
        int wave = tid >> 6, lane = tid & 63;
        if (lane == 0) red[wave] = best;
        __syncthreads();
        if (tid == 0) {
            u64 m = red[0];
            for (int w = 1; w < 4; ++w) m = red[w] < m ? red[w] : m;
            chosen[p] = (int)(u32)m;
            support[b * 9 + p] = chosen[p];
        }
        __syncthreads();
    }
}

// ---------------- d2 + softmax reweight -> pred_score ----------------
__global__ void k_final(const u16* __restrict__ Ah, const u16* __restrict__ Al,
                        const float* __restrict__ bank, const float* __restrict__ ynorm,
                        const float* __restrict__ xnorm, const int* __restrict__ mprow,
                        const int* __restrict__ support, const float* __restrict__ score,
                        float* __restrict__ out_score) {
    int b = blockIdx.x;
    int wave = threadIdx.x >> 6, lane = threadIdx.x & 63;
    __shared__ float d2s[9];
    int row = mprow[b];
    float xn = xnorm[row];
    for (int s = wave; s < 9; s += 4) {
        int sup = support[b * 9 + s];
        float acc = 0.f;
        for (int p = 0; p < 24; ++p) {
            int k = p * 64 + lane;
            float e = bf2f(Ah[(size_t)row * D_ + k]) + bf2f(Al[(size_t)row * D_ + k]);
            acc += e * bank[(size_t)sup * D_ + k];
        }
        for (int msk = 1; msk < 64; msk <<= 1) acc += __shfl_xor(acc, msk, 64);
        if (lane == 0) d2s[s] = sqrtf(fmaxf(xn - 2.f * acc + ynorm[sup], 0.f));
    }
    __syncthreads();
    if (threadIdx.x == 0) {
        float mx = d2s[0];
        for (int i = 1; i < 9; ++i) mx = fmaxf(mx, d2s[i]);
        float den = 0.f;
        for (int i = 0; i < 9; ++i) den += expf(d2s[i] - mx);
        float w = 1.f - expf(d2s[0] - mx) / den;
        out_score[b] = w * score[b];
    }
}

// ---------------- bilinear upsample 28->224 ----------------
__global__ void k_upsample(const float* __restrict__ ps, float* __restrict__ U) {
    int idx = blockIdx.x * 256 + threadIdx.x;
    if (idx >= B_ * IMG_ * IMG_) return;
    int x = idx % IMG_, y = (idx / IMG_) % IMG_, b = idx / (IMG_ * IMG_);
    float sx = x * 0.125f - 0.4375f, sy = y * 0.125f - 0.4375f;
    int ix = (int)floorf(sx), iy = (int)floorf(sy);
    float fx = sx - ix, fy = sy - iy;
    int x0 = min(max(ix, 0), 27), x1 = min(max(ix + 1, 0), 27);
    int y0 = min(max(iy, 0), 27), y1 = min(max(iy + 1, 0), 27);
    const float* p = ps + b * P_;
    U[idx] = (1.f - fy) * ((1.f - fx) * p[y0 * 28 + x0] + fx * p[y0 * 28 + x1])
           + fy * ((1.f - fx) * p[y1 * 28 + x0] + fx * p[y1 * 28 + x1]);
}

// ---------------- separable gaussian blur, reflect pad ----------------
__global__ void k_blurh(const float* __restrict__ U, float* __restrict__ T) {
    __shared__ float g[KS_];
    __shared__ float gs;
    int tid = threadIdx.x;
    if (tid < KS_) { float d = tid - 16.f; g[tid] = expf(-(d * d) / 32.0f); }
    __syncthreads();
    if (tid == 0) { float s = 0.f; for (int i = 0; i < KS_; ++i) s += g[i]; gs = 1.f / s; }
    __syncthreads();
    int idx = blockIdx.x * 256 + tid;
    if (idx >= B_ * IMG_ * IMG_) return;
    int x = idx % IMG_, rowbase = idx - x;
    float a = 0.f;
    for (int t = 0; t < KS_; ++t) {
        int xx = x + t - 16;
        xx = xx < 0 ? -xx : (xx > 223 ? 446 - xx : xx);
        a += g[t] * U[rowbase + xx];
    }
    T[idx] = a * gs;
}
__global__ void k_blurv(const float* __restrict__ T, float* __restrict__ out) {
    __shared__ float g[KS_];
    __shared__ float gs;
    int tid = threadIdx.x;
    if (tid < KS_) { float d = tid - 16.f; g[tid] = expf(-(d * d) / 32.0f); }
    __syncthreads();
    if (tid == 0) { float s = 0.f; for (int i = 0; i < KS_; ++i) s += g[i]; gs = 1.f / s; }
    __syncthreads();
    int idx = blockIdx.x * 256 + tid;
    if (idx >= B_ * IMG_ * IMG_) return;
    int x = idx % IMG_, y = (idx / IMG_) % IMG_, b = idx / (IMG_ * IMG_);
    float a = 0.f;
    for (int t = 0; t < KS_; ++t) {
        int yy = y + t - 16;
        yy = yy < 0 ? -yy : (yy > 223 ? 446 - yy : yy);
        a += g[t] * T[(b * IMG_ + yy) * IMG_ + x];
    }
    out[idx] = a * gs;
}

// ---------------- launch ----------------
extern "C" void kernel_launch(void* const* d_in, const int* in_sizes, int n_in,
                              void* d_out, int out_size, void* d_ws, size_t ws_size,
                              hipStream_t stream) {
    const float* feat1 = (const float*)d_in[0];
    const float* feat2 = (const float*)d_in[1];
    const float* bank  = (const float*)d_in[2];
    float* out = (float*)d_out;
    char* ws = (char*)d_ws;

    size_t o = 0;
    u16* Ah = (u16*)(ws + o); o += (size_t)N_ * D_ * 2;
    u16* Al = (u16*)(ws + o); o += (size_t)N_ * D_ * 2;
    size_t o_Bh = o;
    u16* Bh = (u16*)(ws + o); o += (size_t)MPAD_ * D_ * 2;
    u16* Bl = (u16*)(ws + o); o += (size_t)MPAD_ * D_ * 2;
    // scratch union: pooled2 (pre-GEMM) / partf (GEMM phase)
    size_t o_scr = o;
    float* pooled2 = (float*)(ws + o_scr);
    float* partf   = (float*)(ws + o_scr);
    size_t r1 = (size_t)MT_ * N_ * 4, r2 = (size_t)B_ * C2_ * 196 * 4;
    o += (r1 > r2 ? r1 : r2);
    float* xnorm = (float*)(ws + o); o += (size_t)N_ * 4;
    float* ynorm = (float*)(ws + o); o += (size_t)MPAD_ * 4;
    float* ps    = (float*)(ws + o); o += (size_t)N_ * 4;
    int* candrow = (int*)(ws + o);   o += 512;
    u64* parte   = (u64*)(ws + o);   o += (size_t)MT_ * 128 * 8;
    float* dnb   = (float*)(ws + o); o += (size_t)B_ * M_ * 4;
    int*   mprow = (int*)(ws + o);   o += 64;
    int*   nnidx = (int*)(ws + o);   o += 64;
    float* score = (float*)(ws + o); o += 64;
    int* support = (int*)(ws + o);   o += 9 * B_ * 4;
    // U/T alias the Bh/Bl region (dead after k_gexact)
    float* U = (float*)(ws + o_Bh);
    float* T = (float*)(ws + o_Bh + (size_t)B_ * IMG_ * IMG_ * 4);

    k_pool2<<<(B_ * C2_ * H2_ * H2_ + 255) / 256, 256, 0, stream>>>(feat2, pooled2);
    k_bank<<<MPAD_, 256, 0, stream>>>(bank, Bh, Bl, ynorm);
    k_embed<<<B_ * 28, 256, 0, stream>>>(feat1, pooled2, Ah, Al, xnorm);
    k_gemm1<<<MT_ * NT_, 256, 0, stream>>>(Ah, Bh, ynorm, partf);
    k_reduce<<<NT_, 128, 0, stream>>>(partf, xnorm, ps);
    k_cand<<<B_, 256, 0, stream>>>(ps, candrow);
    k_gexact<<<MT_, 256, 0, stream>>>(Ah, Al, Bh, Bl, ynorm, candrow, parte);
    k_pick<<<1, 128, 0, stream>>>(parte, xnorm, candrow, mprow, nnidx, score);
    k_dnb<<<(M_ + 3) / 4, 256, 0, stream>>>(bank, ynorm, nnidx, dnb);
    k_top9<<<B_, 256, 0, stream>>>(dnb, support);
    k_final<<<B_, 256, 0, stream>>>(Ah, Al, bank, ynorm, xnorm, mprow, support, score,
                                    out + (size_t)B_ * IMG_ * IMG_);
    k_upsample<<<(B_ * IMG_ * IMG_ + 255) / 256, 256, 0, stream>>>(ps, U);
    k_blurh<<<(B_ * IMG_ * IMG_ + 255) / 256, 256, 0, stream>>>(U, T);
    k_blurv<<<(B_ * IMG_ * IMG_ + 255) / 256, 256, 0, stream>>>(T, out);
}

// Round 4
// 1532.169 us; speedup vs baseline: 1.9951x; 1.3343x over previous
//
#include <hip/hip_runtime.h>
#include <stdint.h>

// ---------------- problem constants ----------------
#define B_    16
#define C1_   512
#define C2_   1024
#define H2_   14
#define D_    1536
#define P_    784          // 28*28
#define N_    12544        // B_*P_
#define M_    15000
#define MPAD_ 15104        // 118*128
#define MT_   118          // m tiles of 128
#define NT_   98           // patch tiles of 128
#define IMG_  224
#define KS_   33

typedef unsigned short u16;
typedef unsigned int   u32;
typedef unsigned long long u64;

// ---------------- helpers ----------------
__device__ __forceinline__ u16 f2bf(float x) {
    u32 u = __float_as_uint(x);
    u = u + 0x7fffu + ((u >> 16) & 1u);   // RNE
    return (u16)(u >> 16);
}
__device__ __forceinline__ float bf2f(u16 h) {
    return __uint_as_float(((u32)h) << 16);
}
__device__ __forceinline__ u32 ordf(float f) {
    u32 u = __float_as_uint(f);
    return (u & 0x80000000u) ? ~u : (u | 0x80000000u);
}
__device__ __forceinline__ float unordf(u32 o) {
    u32 u = (o & 0x80000000u) ? (o ^ 0x80000000u) : ~o;
    return __uint_as_float(u);
}

// ---------------- avg-pool feat2 -> pooled2 [16,1024,14,14] ----------------
__global__ void k_pool2(const float* __restrict__ feat2, float* __restrict__ pooled2) {
    int idx = blockIdx.x * 256 + threadIdx.x;
    if (idx >= B_ * C2_ * H2_ * H2_) return;
    int x = idx % 14, y = (idx / 14) % 14, bc = idx / 196;
    const float* src = feat2 + (size_t)bc * 196;
    float s = 0.f;
    for (int dy = -1; dy <= 1; ++dy) {
        int yy = y + dy; if (yy < 0 || yy > 13) continue;
        for (int dx = -1; dx <= 1; ++dx) {
            int xx = x + dx; if (xx < 0 || xx > 13) continue;
            s += src[yy * 14 + xx];
        }
    }
    pooled2[idx] = s * (1.f / 9.f);
}

// ---------------- bank split (hi/lo bf16) + norms, with padding ----------------
__global__ void k_bank(const float* __restrict__ bank, u16* __restrict__ Bh,
                       u16* __restrict__ Bl, float* __restrict__ ynorm) {
    int m = blockIdx.x, tid = threadIdx.x;
    float nrm = 0.f;
    if (m < M_) {
        for (int p = 0; p < 6; ++p) {
            int c = p * 256 + tid;
            float v = bank[(size_t)m * D_ + c];
            u16 h = f2bf(v);
            Bh[(size_t)m * D_ + c] = h;
            Bl[(size_t)m * D_ + c] = f2bf(v - bf2f(h));
            nrm += v * v;
        }
    } else {
        for (int p = 0; p < 6; ++p) {
            int c = p * 256 + tid;
            Bh[(size_t)m * D_ + c] = 0; Bl[(size_t)m * D_ + c] = 0;
        }
    }
    __shared__ float red[4];
    for (int off = 32; off; off >>= 1) nrm += __shfl_down(nrm, off, 64);
    int wave = tid >> 6, lane = tid & 63;
    if (lane == 0) red[wave] = nrm;
    __syncthreads();
    if (tid == 0) {
        float t = red[0] + red[1] + red[2] + red[3];
        ynorm[m] = (m < M_) ? t : __uint_as_float(0x7f800000u);  // +inf pad
    }
}

// ---------------- embedding build, row-block version ----------------
__global__ __launch_bounds__(256)
void k_embed(const float* __restrict__ feat1, const float* __restrict__ pooled2,
             u16* __restrict__ Ah, u16* __restrict__ Al, float* __restrict__ xnorm) {
    __shared__ float sF[3 * 64 * 29];   // [r][c][x] padded to 29
    __shared__ float xn[28];
    const int tid = threadIdx.x, lane = tid & 63, wave = tid >> 6;
    const int b = blockIdx.x / 28, y = blockIdx.x % 28;
    const int brow = b * P_ + y * 28;
    if (tid < 28) xn[tid] = 0.f;

    float sy = y * 0.5f - 0.25f;
    int iy = (int)floorf(sy);
    float fy = sy - iy;
    int y0 = min(max(iy, 0), 13), y1 = min(max(iy + 1, 0), 13);
    __syncthreads();

    // ---- feat1 channels (512) in 8 chunks of 64 ----
    for (int cc = 0; cc < 8; ++cc) {
        for (int j = tid; j < 3 * 64 * 28; j += 256) {
            int x = j % 28, c = (j / 28) % 64, r = j / (28 * 64);
            int yy = y - 1 + r;
            float v = 0.f;
            if (yy >= 0 && yy < 28)
                v = feat1[((size_t)(b * C1_ + cc * 64 + c)) * 784 + yy * 28 + x];
            sF[(r * 64 + c) * 29 + x] = v;
        }
        __syncthreads();
        for (int it = 0; it < 7; ++it) {
            int x = it * 4 + wave, c = lane;
            float s = 0.f;
#pragma unroll
            for (int r = 0; r < 3; ++r) {
                int base = (r * 64 + c) * 29;
                if (x > 0) s += sF[base + x - 1];
                s += sF[base + x];
                if (x < 27) s += sF[base + x + 1];
            }
            float v = s * (1.f / 9.f);
            int col = cc * 64 + c;
            size_t off = (size_t)(brow + x) * D_ + col;
            u16 h = f2bf(v);
            Ah[off] = h; Al[off] = f2bf(v - bf2f(h));
            float vv = v * v;
            for (int m = 1; m < 64; m <<= 1) vv += __shfl_xor(vv, m, 64);
            if (lane == 0) atomicAdd(&xn[x], vv);
        }
        __syncthreads();
    }

    // ---- pooled2 channels (1024) in 16 chunks of 64, bilinear ----
    for (int cc = 0; cc < 16; ++cc) {
        for (int it = 0; it < 7; ++it) {
            int x = it * 4 + wave, c = lane;
            const float* sp = pooled2 + ((size_t)(b * C2_ + cc * 64 + c)) * 196;
            float sx = x * 0.5f - 0.25f;
            int ix = (int)floorf(sx);
            float fx = sx - ix;
            int x0 = min(max(ix, 0), 13), x1 = min(max(ix + 1, 0), 13);
            float v = (1.f - fy) * ((1.f - fx) * sp[y0 * 14 + x0] + fx * sp[y0 * 14 + x1])
                    + fy * ((1.f - fx) * sp[y1 * 14 + x0] + fx * sp[y1 * 14 + x1]);
            int col = C1_ + cc * 64 + c;
            size_t off = (size_t)(brow + x) * D_ + col;
            u16 h = f2bf(v);
            Ah[off] = h; Al[off] = f2bf(v - bf2f(h));
            float vv = v * v;
            for (int m = 1; m < 64; m <<= 1) vv += __shfl_xor(vv, m, 64);
            if (lane == 0) atomicAdd(&xn[x], vv);
        }
    }
    __syncthreads();
    if (tid < 28) xnorm[brow + tid] = xn[tid];
}

// ---------------- phase-1: bf16 hi-only GEMM, m97-style, value-min epilogue ----
// 128x128 tile, BK=32, 16x16x32 MFMA, each wave computes 64x64 (4x4 tiles) so
// LDS-read:MFMA = ~256:310 cyc per block-kt (balanced; the R3 direct-global-B
// variant was TA-transaction-bound on 32-line gathers).
// LDS: row = 32 u16 = 64 B; 16B-chunk slot = chunk ^ (row&3) (granule XOR
// swizzle, applied source-side at staging) -> fragment reads spread uniformly
// over all 8 granules (8 lanes each) -> conflict-free.
typedef __bf16 bf16x8 __attribute__((ext_vector_type(8)));
typedef float  f32x4  __attribute__((ext_vector_type(4)));
typedef float  f32x16 __attribute__((ext_vector_type(16)));

__global__ __launch_bounds__(256)
void k_gemm1(const u16* __restrict__ Ah, const u16* __restrict__ Bh,
             const float* __restrict__ ynorm, float* __restrict__ partf) {
    __shared__ u16 sA[128 * 32];       // 8 KB
    __shared__ u16 sB[128 * 32];       // 8 KB
    __shared__ float smin[128][2];

    const int tid = threadIdx.x, lane = tid & 63, wave = tid >> 6;
    // grouped tile order for B locality
    const int GM = 8, nig = GM * NT_;
    const int grp = blockIdx.x / nig, rem = blockIdx.x - grp * nig;
    const int first = grp * GM;
    const int gsz = (MT_ - first) < GM ? (MT_ - first) : GM;
    const int mt = first + rem % gsz;
    const int pt = rem / gsz;
    const int p0 = pt * 128, m0 = mt * 128;

    f32x4 acc[4][4];
#pragma unroll
    for (int i = 0; i < 4; ++i)
#pragma unroll
        for (int j = 0; j < 4; ++j)
#pragma unroll
            for (int e = 0; e < 4; ++e) acc[i][j][e] = 0.f;

    // staging assignment: wave stages slabs {wave*2, wave*2+1} for sA and sB
    const int srow = lane >> 2;                   // 0..15 row within slab
    const int schunk = (lane & 3) ^ (srow & 3);   // source-side swizzle
    // fragment read params
    const int fr = lane & 15;                     // row (A) / col (B) in 16-tile
    const int q  = lane >> 4;                     // k-quad 0..3
    const int slot8 = (q ^ (fr & 3)) * 8;         // swizzled chunk offset (u16)
    const int wr = (wave >> 1) * 64, wc = (wave & 1) * 64;

    for (int kt = 0; kt < 48; ++kt) {
        const int k0 = kt * 32;
#pragma unroll
        for (int s = 0; s < 2; ++s) {
            const int slab = wave * 2 + s;
            const int row = slab * 16 + srow;
            const u16* ga = Ah + (size_t)(p0 + row) * D_ + k0 + schunk * 8;
            __builtin_amdgcn_global_load_lds((const __attribute__((address_space(1))) void*)ga,
                (__attribute__((address_space(3))) void*)&sA[slab * 512], 16, 0, 0);
            const u16* gb = Bh + (size_t)(m0 + row) * D_ + k0 + schunk * 8;
            __builtin_amdgcn_global_load_lds((const __attribute__((address_space(1))) void*)gb,
                (__attribute__((address_space(3))) void*)&sB[slab * 512], 16, 0, 0);
        }
        __syncthreads();
        bf16x8 af[4], bfr[4];
#pragma unroll
        for (int ti = 0; ti < 4; ++ti)
            af[ti] = *(const bf16x8*)&sA[(wr + ti * 16 + fr) * 32 + slot8];
#pragma unroll
        for (int tj = 0; tj < 4; ++tj)
            bfr[tj] = *(const bf16x8*)&sB[(wc + tj * 16 + fr) * 32 + slot8];
#pragma unroll
        for (int ti = 0; ti < 4; ++ti)
#pragma unroll
            for (int tj = 0; tj < 4; ++tj)
                acc[ti][tj] = __builtin_amdgcn_mfma_f32_16x16x32_bf16(af[ti], bfr[tj], acc[ti][tj], 0, 0, 0);
        __syncthreads();
    }

    // epilogue: C/D layout (16x16): col = lane&15 (bank col), row = q*4 + reg.
    float yn[4];
#pragma unroll
    for (int tj = 0; tj < 4; ++tj) yn[tj] = ynorm[m0 + wc + tj * 16 + fr];
#pragma unroll
    for (int ti = 0; ti < 4; ++ti) {
#pragma unroll
        for (int reg = 0; reg < 4; ++reg) {
            float v = __uint_as_float(0x7f800000u);
#pragma unroll
            for (int tj = 0; tj < 4; ++tj)
                v = fminf(v, yn[tj] - 2.0f * acc[ti][tj][reg]);
#pragma unroll
            for (int msk = 1; msk < 16; msk <<= 1)
                v = fminf(v, __shfl_xor(v, msk, 64));
            if (fr == 0) smin[wr + ti * 16 + q * 4 + reg][wave & 1] = v;
        }
    }
    __syncthreads();
    if (tid < 128)
        partf[(size_t)mt * N_ + p0 + tid] = fminf(smin[tid][0], smin[tid][1]);
}

// ---------------- reduce partial mins -> approx patch scores ----------------
__global__ void k_reduce(const float* __restrict__ partf, const float* __restrict__ xnorm,
                         float* __restrict__ ps) {
    int n = blockIdx.x * 128 + threadIdx.x;
    float best = __uint_as_float(0x7f800000u);
    for (int t = 0; t < MT_; ++t)
        best = fminf(best, partf[(size_t)t * N_ + n]);
    ps[n] = sqrtf(fmaxf(best + xnorm[n], 0.f));
}

// ---------------- per-image approx top-8 patches (candidates) ----------------
__global__ void k_cand(const float* __restrict__ ps, int* __restrict__ candrow) {
    int b = blockIdx.x, tid = threadIdx.x;
    __shared__ int chosen[8];
    __shared__ u64 red[4];
    for (int j = 0; j < 8; ++j) {
        u64 best = 0;
        for (int p = tid; p < P_; p += 256) {
            bool skip = false;
            for (int q = 0; q < j; ++q) if (chosen[q] == p) skip = true;
            if (skip) continue;
            u64 pk = ((u64)ordf(ps[b * P_ + p]) << 32) | (u32)(~(u32)p);
            best = pk > best ? pk : best;
        }
        for (int msk = 1; msk < 64; msk <<= 1) {
            u64 o = __shfl_xor(best, msk, 64);
            best = o > best ? o : best;
        }
        int wave = tid >> 6, lane = tid & 63;
        if (lane == 0) red[wave] = best;
        __syncthreads();
        if (tid == 0) {
            u64 m = red[0];
            for (int w = 1; w < 4; ++w) m = red[w] > m ? red[w] : m;
            int p = (int)(~(u32)m);
            chosen[j] = p;
            candrow[b * 8 + j] = b * P_ + p;
        }
        __syncthreads();
    }
}

// ---------------- phase-2: exact 3-term split GEMM over 128 candidate rows ----
__global__ __launch_bounds__(256)
void k_gexact(const u16* __restrict__ Ah, const u16* __restrict__ Al,
              const u16* __restrict__ Bh, const u16* __restrict__ Bl,
              const float* __restrict__ ynorm, const int* __restrict__ candrow,
              u64* __restrict__ parte) {
    __shared__ u16 sA[2][128 * 32];
    __shared__ u16 sB[2][128 * 32];
    __shared__ u64 smin[128][2];
    __shared__ int scand[128];

    const int tid = threadIdx.x;
    const int lane = tid & 63, wave = tid >> 6;
    const int mt = blockIdx.x;
    const int m0 = mt * 128;
    if (tid < 128) scand[tid] = candrow[tid];

    f32x16 acc[2][2];
#pragma unroll
    for (int i = 0; i < 2; ++i)
#pragma unroll
        for (int j = 0; j < 2; ++j)
#pragma unroll
            for (int e = 0; e < 16; ++e) acc[i][j][e] = 0.f;

    const int srow = lane >> 2;
    const int scol = ((lane & 3) ^ ((lane >> 3) & 3)) * 8;
    const int wr = (wave >> 1) * 64, wc = (wave & 1) * 64;
    const int rA = lane & 31;
    const int sw = (lane >> 1) & 3;
    __syncthreads();

    for (int kt = 0; kt < 48; ++kt) {
        const int k0 = kt * 32;
#pragma unroll
        for (int s = 0; s < 2; ++s) {
            const int slab = wave * 2 + s;
            const int row = slab * 16 + srow;
            const int grow = scand[row];
            const u16* ga = Ah + (size_t)grow * D_ + k0 + scol;
            __builtin_amdgcn_global_load_lds((const __attribute__((address_space(1))) void*)ga,
                (__attribute__((address_space(3))) void*)&sA[0][slab * 512], 16, 0, 0);
            const u16* ga2 = Al + (size_t)grow * D_ + k0 + scol;
            __builtin_amdgcn_global_load_lds((const __attribute__((address_space(1))) void*)ga2,
                (__attribute__((address_space(3))) void*)&sA[1][slab * 512], 16, 0, 0);
            const u16* gb = Bh + (size_t)(m0 + row) * D_ + k0 + scol;
            __builtin_amdgcn_global_load_lds((const __attribute__((address_space(1))) void*)gb,
                (__attribute__((address_space(3))) void*)&sB[0][slab * 512], 16, 0, 0);
            const u16* gb2 = Bl + (size_t)(m0 + row) * D_ + k0 + scol;
            __builtin_amdgcn_global_load_lds((const __attribute__((address_space(1))) void*)gb2,
                (__attribute__((address_space(3))) void*)&sB[1][slab * 512], 16, 0, 0);
        }
        __syncthreads();
#pragma unroll
        for (int ks = 0; ks < 2; ++ks) {
            const int co = ((ks * 2 + (lane >> 5)) ^ sw) * 8;
            bf16x8 ah0 = *(const bf16x8*)&sA[0][(wr + rA) * 32 + co];
            bf16x8 ah1 = *(const bf16x8*)&sA[0][(wr + 32 + rA) * 32 + co];
            bf16x8 al0 = *(const bf16x8*)&sA[1][(wr + rA) * 32 + co];
            bf16x8 al1 = *(const bf16x8*)&sA[1][(wr + 32 + rA) * 32 + co];
            bf16x8 bh0 = *(const bf16x8*)&sB[0][(wc + rA) * 32 + co];
            bf16x8 bh1 = *(const bf16x8*)&sB[0][(wc + 32 + rA) * 32 + co];
            bf16x8 bl0 = *(const bf16x8*)&sB[1][(wc + rA) * 32 + co];
            bf16x8 bl1 = *(const bf16x8*)&sB[1][(wc + 32 + rA) * 32 + co];
            acc[0][0] = __builtin_amdgcn_mfma_f32_32x32x16_bf16(ah0, bh0, acc[0][0], 0, 0, 0);
            acc[0][1] = __builtin_amdgcn_mfma_f32_32x32x16_bf16(ah0, bh1, acc[0][1], 0, 0, 0);
            acc[1][0] = __builtin_amdgcn_mfma_f32_32x32x16_bf16(ah1, bh0, acc[1][0], 0, 0, 0);
            acc[1][1] = __builtin_amdgcn_mfma_f32_32x32x16_bf16(ah1, bh1, acc[1][1], 0, 0, 0);
            acc[0][0] = __builtin_amdgcn_mfma_f32_32x32x16_bf16(ah0, bl0, acc[0][0], 0, 0, 0);
            acc[0][1] = __builtin_amdgcn_mfma_f32_32x32x16_bf16(ah0, bl1, acc[0][1], 0, 0, 0);
            acc[1][0] = __builtin_amdgcn_mfma_f32_32x32x16_bf16(ah1, bl0, acc[1][0], 0, 0, 0);
            acc[1][1] = __builtin_amdgcn_mfma_f32_32x32x16_bf16(ah1, bl1, acc[1][1], 0, 0, 0);
            acc[0][0] = __builtin_amdgcn_mfma_f32_32x32x16_bf16(al0, bh0, acc[0][0], 0, 0, 0);
            acc[0][1] = __builtin_amdgcn_mfma_f32_32x32x16_bf16(al0, bh1, acc[0][1], 0, 0, 0);
            acc[1][0] = __builtin_amdgcn_mfma_f32_32x32x16_bf16(al1, bh0, acc[1][0], 0, 0, 0);
            acc[1][1] = __builtin_amdgcn_mfma_f32_32x32x16_bf16(al1, bh1, acc[1][1], 0, 0, 0);
        }
        __syncthreads();
    }

    const int wrB = wave >> 1, wcB = wave & 1;
    const int half = lane >> 5, c32 = lane & 31;
    float yn[2];
    yn[0] = ynorm[m0 + wcB * 64 + c32];
    yn[1] = ynorm[m0 + wcB * 64 + 32 + c32];
#pragma unroll
    for (int ti = 0; ti < 2; ++ti) {
#pragma unroll
        for (int reg = 0; reg < 16; ++reg) {
            const int rloc = wrB * 64 + ti * 32 + 4 * half + (reg & 3) + 8 * (reg >> 2);
            u64 best = ~0ull;
#pragma unroll
            for (int tj = 0; tj < 2; ++tj) {
                float v = yn[tj] - 2.0f * acc[ti][tj][reg];
                u32 col = (u32)(m0 + wcB * 64 + tj * 32 + c32);
                u64 pk = ((u64)ordf(v) << 32) | col;
                best = pk < best ? pk : best;
            }
#pragma unroll
            for (int msk = 1; msk < 32; msk <<= 1) {
                u64 o = __shfl_xor(best, msk, 64);
                best = o < best ? o : best;
            }
            if (c32 == 0) smin[rloc][wcB] = best;
        }
    }
    __syncthreads();
    if (tid < 128) {
        u64 a = smin[tid][0], b = smin[tid][1];
        parte[(size_t)mt * 128 + tid] = a < b ? a : b;
    }
}

// ---------------- pick exact winner per image ----------------
__global__ void k_pick(const u64* __restrict__ parte, const float* __restrict__ xnorm,
                       const int* __restrict__ candrow, int* __restrict__ mprow,
                       int* __restrict__ nnidx, float* __restrict__ score) {
    __shared__ float sps[128];
    __shared__ int sloc[128];
    int i = threadIdx.x;   // 0..127
    u64 best = ~0ull;
    for (int t = 0; t < MT_; ++t) {
        u64 v = parte[(size_t)t * 128 + i];
        best = v < best ? v : best;
    }
    float val = unordf((u32)(best >> 32)) + xnorm[candrow[i]];
    sps[i] = sqrtf(fmaxf(val, 0.f));
    sloc[i] = (int)(u32)best;
    __syncthreads();
    if (i < B_) {
        float bs = -1.f; int bj = 0; int brw = 1 << 30;
        for (int j = 0; j < 8; ++j) {
            int idx = i * 8 + j;
            float v = sps[idx];
            int row = candrow[idx];
            if (v > bs || (v == bs && row < brw)) { bs = v; bj = idx; brw = row; }
        }
        mprow[i] = brw;
        nnidx[i] = sloc[bj];
        score[i] = bs;
    }
}

// ---------------- d_nb: dist(bank[nn_index[b]], bank) exact fp32 ----------------
__global__ void k_dnb(const float* __restrict__ bank, const float* __restrict__ ynorm,
                      const int* __restrict__ nnidx, float* __restrict__ dnb) {
    int wave = threadIdx.x >> 6, lane = threadIdx.x & 63;
    int m = blockIdx.x * 4 + wave;
    if (m >= M_) return;
    const float4* br = (const float4*)(bank + (size_t)m * D_);
    float acc[B_];
#pragma unroll
    for (int b = 0; b < B_; ++b) acc[b] = 0.f;
#pragma unroll
    for (int p = 0; p < 6; ++p) {
        float4 c = br[p * 64 + lane];
#pragma unroll
        for (int b = 0; b < B_; ++b) {
            const float4* nr = (const float4*)(bank + (size_t)nnidx[b] * D_);
            float4 a = nr[p * 64 + lane];
            acc[b] += a.x * c.x + a.y * c.y + a.z * c.z + a.w * c.w;
        }
    }
    float ym = ynorm[m];
    float keep = 0.f;
#pragma unroll
    for (int b = 0; b < B_; ++b) {
        float v = acc[b];
        for (int msk = 1; msk < 64; msk <<= 1) v += __shfl_xor(v, msk, 64);
        if (lane == b) keep = v;
    }
    if (lane < B_) {
        float ynn = ynorm[nnidx[lane]];
        dnb[lane * M_ + m] = sqrtf(fmaxf(ynn - 2.f * keep + ym, 0.f));
    }
}

// ---------------- top-9 smallest of dnb per image ----------------
__global__ void k_top9(const float* __restrict__ dnb, int* __restrict__ support) {
    int b = blockIdx.x, tid = threadIdx.x;
    __shared__ int chosen[9];
    __shared__ u64 red[4];
    for (int p = 0; p < 9; ++p) {
        u64 best = ~0ull;
        for (int m = tid; m < M_; m += 256) {
            bool skip = false;
            for (int q = 0; q < p; ++q) if (chosen[q] == m) skip = true;
            if (skip) continue;
            float v = dnb[b * M_ + m];
            u64 pk = ((u64)ordf(v) << 32) | (u32)m;
            best = pk < best ? pk : best;
        }
        for (int msk = 1; msk < 64; msk <<= 1) {
            u64 o = __shfl_xor(best, msk, 64);
            best = o < best ? o : best;
        }
        int wave = tid >> 6, lane = tid & 63;
        if (lane == 0) red[wave] = best;
        __syncthreads();
        if (tid == 0) {
            u64 m = red[0];
            for (int w = 1; w < 4; ++w) m = red[w] < m ? red[w] : m;
            chosen[p] = (int)(u32)m;
            support[b * 9 + p] = chosen[p];
        }
        __syncthreads();
    }
}

// ---------------- d2 + softmax reweight -> pred_score ----------------
__global__ void k_final(const u16* __restrict__ Ah, const u16* __restrict__ Al,
                        const float* __restrict__ bank, const float* __restrict__ ynorm,
                        const float* __restrict__ xnorm, const int* __restrict__ mprow,
                        const int* __restrict__ support, const float* __restrict__ score,
                        float* __restrict__ out_score) {
    int b = blockIdx.x;
    int wave = threadIdx.x >> 6, lane = threadIdx.x & 63;
    __shared__ float d2s[9];
    int row = mprow[b];
    float xn = xnorm[row];
    for (int s = wave; s < 9; s += 4) {
        int sup = support[b * 9 + s];
        float acc = 0.f;
        for (int p = 0; p < 24; ++p) {
            int k = p * 64 + lane;
            float e = bf2f(Ah[(size_t)row * D_ + k]) + bf2f(Al[(size_t)row * D_ + k]);
            acc += e * bank[(size_t)sup * D_ + k];
        }
        for (int msk = 1; msk < 64; msk <<= 1) acc += __shfl_xor(acc, msk, 64);
        if (lane == 0) d2s[s] = sqrtf(fmaxf(xn - 2.f * acc + ynorm[sup], 0.f));
    }
    __syncthreads();
    if (threadIdx.x == 0) {
        float mx = d2s[0];
        for (int i = 1; i < 9; ++i) mx = fmaxf(mx, d2s[i]);
        float den = 0.f;
        for (int i = 0; i < 9; ++i) den += expf(d2s[i] - mx);
        float w = 1.f - expf(d2s[0] - mx) / den;
        out_score[b] = w * score[b];
    }
}

// ---------------- bilinear upsample 28->224 ----------------
__global__ void k_upsample(const float* __restrict__ ps, float* __restrict__ U) {
    int idx = blockIdx.x * 256 + threadIdx.x;
    if (idx >= B_ * IMG_ * IMG_) return;
    int x = idx % IMG_, y = (idx / IMG_) % IMG_, b = idx / (IMG_ * IMG_);
    float sx = x * 0.125f - 0.4375f, sy = y * 0.125f - 0.4375f;
    int ix = (int)floorf(sx), iy = (int)floorf(sy);
    float fx = sx - ix, fy = sy - iy;
    int x0 = min(max(ix, 0), 27), x1 = min(max(ix + 1, 0), 27);
    int y0 = min(max(iy, 0), 27), y1 = min(max(iy + 1, 0), 27);
    const float* p = ps + b * P_;
    U[idx] = (1.f - fy) * ((1.f - fx) * p[y0 * 28 + x0] + fx * p[y0 * 28 + x1])
           + fy * ((1.f - fx) * p[y1 * 28 + x0] + fx * p[y1 * 28 + x1]);
}

// ---------------- separable gaussian blur, reflect pad ----------------
__global__ void k_blurh(const float* __restrict__ U, float* __restrict__ T) {
    __shared__ float g[KS_];
    __shared__ float gs;
    int tid = threadIdx.x;
    if (tid < KS_) { float d = tid - 16.f; g[tid] = expf(-(d * d) / 32.0f); }
    __syncthreads();
    if (tid == 0) { float s = 0.f; for (int i = 0; i < KS_; ++i) s += g[i]; gs = 1.f / s; }
    __syncthreads();
    int idx = blockIdx.x * 256 + tid;
    if (idx >= B_ * IMG_ * IMG_) return;
    int x = idx % IMG_, rowbase = idx - x;
    float a = 0.f;
    for (int t = 0; t < KS_; ++t) {
        int xx = x + t - 16;
        xx = xx < 0 ? -xx : (xx > 223 ? 446 - xx : xx);
        a += g[t] * U[rowbase + xx];
    }
    T[idx] = a * gs;
}
__global__ void k_blurv(const float* __restrict__ T, float* __restrict__ out) {
    __shared__ float g[KS_];
    __shared__ float gs;
    int tid = threadIdx.x;
    if (tid < KS_) { float d = tid - 16.f; g[tid] = expf(-(d * d) / 32.0f); }
    __syncthreads();
    if (tid == 0) { float s = 0.f; for (int i = 0; i < KS_; ++i) s += g[i]; gs = 1.f / s; }
    __syncthreads();
    int idx = blockIdx.x * 256 + tid;
    if (idx >= B_ * IMG_ * IMG_) return;
    int x = idx % IMG_, y = (idx / IMG_) % IMG_, b = idx / (IMG_ * IMG_);
    float a = 0.f;
    for (int t = 0; t < KS_; ++t) {
        int yy = y + t - 16;
        yy = yy < 0 ? -yy : (yy > 223 ? 446 - yy : yy);
        a += g[t] * T[(b * IMG_ + yy) * IMG_ + x];
    }
    out[idx] = a * gs;
}

// ---------------- launch ----------------
extern "C" void kernel_launch(void* const* d_in, const int* in_sizes, int n_in,
                              void* d_out, int out_size, void* d_ws, size_t ws_size,
                              hipStream_t stream) {
    const float* feat1 = (const float*)d_in[0];
    const float* feat2 = (const float*)d_in[1];
    const float* bank  = (const float*)d_in[2];
    float* out = (float*)d_out;
    char* ws = (char*)d_ws;

    size_t o = 0;
    u16* Ah = (u16*)(ws + o); o += (size_t)N_ * D_ * 2;
    u16* Al = (u16*)(ws + o); o += (size_t)N_ * D_ * 2;
    size_t o_Bh = o;
    u16* Bh = (u16*)(ws + o); o += (size_t)MPAD_ * D_ * 2;
    u16* Bl = (u16*)(ws + o); o += (size_t)MPAD_ * D_ * 2;
    // scratch union: pooled2 (pre-GEMM) / partf (GEMM phase)
    size_t o_scr = o;
    float* pooled2 = (float*)(ws + o_scr);
    float* partf   = (float*)(ws + o_scr);
    size_t r1 = (size_t)MT_ * N_ * 4, r2 = (size_t)B_ * C2_ * 196 * 4;
    o += (r1 > r2 ? r1 : r2);
    float* xnorm = (float*)(ws + o); o += (size_t)N_ * 4;
    float* ynorm = (float*)(ws + o); o += (size_t)MPAD_ * 4;
    float* ps    = (float*)(ws + o); o += (size_t)N_ * 4;
    int* candrow = (int*)(ws + o);   o += 512;
    u64* parte   = (u64*)(ws + o);   o += (size_t)MT_ * 128 * 8;
    float* dnb   = (float*)(ws + o); o += (size_t)B_ * M_ * 4;
    int*   mprow = (int*)(ws + o);   o += 64;
    int*   nnidx = (int*)(ws + o);   o += 64;
    float* score = (float*)(ws + o); o += 64;
    int* support = (int*)(ws + o);   o += 9 * B_ * 4;
    // U/T alias the Bh/Bl region (dead after k_gexact)
    float* U = (float*)(ws + o_Bh);
    float* T = (float*)(ws + o_Bh + (size_t)B_ * IMG_ * IMG_ * 4);

    k_pool2<<<(B_ * C2_ * H2_ * H2_ + 255) / 256, 256, 0, stream>>>(feat2, pooled2);
    k_bank<<<MPAD_, 256, 0, stream>>>(bank, Bh, Bl, ynorm);
    k_embed<<<B_ * 28, 256, 0, stream>>>(feat1, pooled2, Ah, Al, xnorm);
    k_gemm1<<<MT_ * NT_, 256, 0, stream>>>(Ah, Bh, ynorm, partf);
    k_reduce<<<NT_, 128, 0, stream>>>(partf, xnorm, ps);
    k_cand<<<B_, 256, 0, stream>>>(ps, candrow);
    k_gexact<<<MT_, 256, 0, stream>>>(Ah, Al, Bh, Bl, ynorm, candrow, parte);
    k_pick<<<1, 128, 0, stream>>>(parte, xnorm, candrow, mprow, nnidx, score);
    k_dnb<<<(M_ + 3) / 4, 256, 0, stream>>>(bank, ynorm, nnidx, dnb);
    k_top9<<<B_, 256, 0, stream>>>(dnb, support);
    k_final<<<B_, 256, 0, stream>>>(Ah, Al, bank, ynorm, xnorm, mprow, support, score,
                                    out + (size_t)B_ * IMG_ * IMG_);
    k_upsample<<<(B_ * IMG_ * IMG_ + 255) / 256, 256, 0, stream>>>(ps, U);
    k_blurh<<<(B_ * IMG_ * IMG_ + 255) / 256, 256, 0, stream>>>(U, T);
    k_blurv<<<(B_ * IMG_ * IMG_ + 255) / 256, 256, 0, stream>>>(T, out);
}

// Round 5
// 1254.559 us; speedup vs baseline: 2.4366x; 1.2213x over previous
//
#include <hip/hip_runtime.h>
#include <stdint.h>

// ---------------- problem constants ----------------
#define B_    16
#define C1_   512
#define C2_   1024
#define H2_   14
#define D_    1536
#define P_    784          // 28*28
#define N_    12544        // B_*P_
#define M_    15000
#define MPAD_ 15104        // padded bank rows
#define MT1_  118          // 128-wide m tiles (k_gexact)
#define MT2_  59           // 256-wide m tiles (k_gemm1)
#define NT_   98           // patch tiles of 128
#define IMG_  224
#define KS_   33

typedef unsigned short u16;
typedef unsigned int   u32;
typedef unsigned long long u64;

// ---------------- helpers ----------------
__device__ __forceinline__ u16 f2bf(float x) {
    u32 u = __float_as_uint(x);
    u = u + 0x7fffu + ((u >> 16) & 1u);   // RNE
    return (u16)(u >> 16);
}
__device__ __forceinline__ float bf2f(u16 h) {
    return __uint_as_float(((u32)h) << 16);
}
__device__ __forceinline__ u32 ordf(float f) {
    u32 u = __float_as_uint(f);
    return (u & 0x80000000u) ? ~u : (u | 0x80000000u);
}
__device__ __forceinline__ float unordf(u32 o) {
    u32 u = (o & 0x80000000u) ? (o ^ 0x80000000u) : ~o;
    return __uint_as_float(u);
}

// ---------------- avg-pool feat2 -> pooled2 [16,1024,14,14] ----------------
__global__ void k_pool2(const float* __restrict__ feat2, float* __restrict__ pooled2) {
    int idx = blockIdx.x * 256 + threadIdx.x;
    if (idx >= B_ * C2_ * H2_ * H2_) return;
    int x = idx % 14, y = (idx / 14) % 14, bc = idx / 196;
    const float* src = feat2 + (size_t)bc * 196;
    float s = 0.f;
    for (int dy = -1; dy <= 1; ++dy) {
        int yy = y + dy; if (yy < 0 || yy > 13) continue;
        for (int dx = -1; dx <= 1; ++dx) {
            int xx = x + dx; if (xx < 0 || xx > 13) continue;
            s += src[yy * 14 + xx];
        }
    }
    pooled2[idx] = s * (1.f / 9.f);
}

// ---------------- bank split (hi/lo bf16) + norms, vectorized ----------------
// 192 threads/block, 8 elems/thread, 16-B uint4 stores (was 2-B scalar).
__global__ __launch_bounds__(192)
void k_bank(const float* __restrict__ bank, u16* __restrict__ Bh,
            u16* __restrict__ Bl, float* __restrict__ ynorm) {
    int m = blockIdx.x, tid = threadIdx.x;
    float nrm = 0.f;
    float v[8];
    if (m < M_) {
        const float4* src = (const float4*)(bank + (size_t)m * D_ + tid * 8);
        float4 a = src[0], b = src[1];
        v[0]=a.x; v[1]=a.y; v[2]=a.z; v[3]=a.w; v[4]=b.x; v[5]=b.y; v[6]=b.z; v[7]=b.w;
#pragma unroll
        for (int i = 0; i < 8; ++i) nrm += v[i] * v[i];
    } else {
#pragma unroll
        for (int i = 0; i < 8; ++i) v[i] = 0.f;
    }
    u32 hw[4], lw[4];
#pragma unroll
    for (int i = 0; i < 4; ++i) {
        u16 h0 = f2bf(v[2*i]),   l0 = f2bf(v[2*i]   - bf2f(h0));
        u16 h1 = f2bf(v[2*i+1]), l1 = f2bf(v[2*i+1] - bf2f(h1));
        hw[i] = (u32)h0 | ((u32)h1 << 16);
        lw[i] = (u32)l0 | ((u32)l1 << 16);
    }
    *(uint4*)(Bh + (size_t)m * D_ + tid * 8) = make_uint4(hw[0], hw[1], hw[2], hw[3]);
    *(uint4*)(Bl + (size_t)m * D_ + tid * 8) = make_uint4(lw[0], lw[1], lw[2], lw[3]);
    __shared__ float red[3];
    for (int off = 32; off; off >>= 1) nrm += __shfl_down(nrm, off, 64);
    int wave = tid >> 6, lane = tid & 63;
    if (lane == 0) red[wave] = nrm;
    __syncthreads();
    if (tid == 0) {
        float t = red[0] + red[1] + red[2];
        ynorm[m] = (m < M_) ? t : __uint_as_float(0x7f800000u);  // +inf pad
    }
}

// ---------------- embedding build, row-block version ----------------
__global__ __launch_bounds__(256)
void k_embed(const float* __restrict__ feat1, const float* __restrict__ pooled2,
             u16* __restrict__ Ah, u16* __restrict__ Al, float* __restrict__ xnorm) {
    __shared__ float sF[3 * 64 * 29];   // [r][c][x] padded to 29
    __shared__ float xn[28];
    const int tid = threadIdx.x, lane = tid & 63, wave = tid >> 6;
    const int b = blockIdx.x / 28, y = blockIdx.x % 28;
    const int brow = b * P_ + y * 28;
    if (tid < 28) xn[tid] = 0.f;

    float sy = y * 0.5f - 0.25f;
    int iy = (int)floorf(sy);
    float fy = sy - iy;
    int y0 = min(max(iy, 0), 13), y1 = min(max(iy + 1, 0), 13);
    __syncthreads();

    // ---- feat1 channels (512) in 8 chunks of 64 ----
    for (int cc = 0; cc < 8; ++cc) {
        for (int j = tid; j < 3 * 64 * 28; j += 256) {
            int x = j % 28, c = (j / 28) % 64, r = j / (28 * 64);
            int yy = y - 1 + r;
            float v = 0.f;
            if (yy >= 0 && yy < 28)
                v = feat1[((size_t)(b * C1_ + cc * 64 + c)) * 784 + yy * 28 + x];
            sF[(r * 64 + c) * 29 + x] = v;
        }
        __syncthreads();
        for (int it = 0; it < 7; ++it) {
            int x = it * 4 + wave, c = lane;
            float s = 0.f;
#pragma unroll
            for (int r = 0; r < 3; ++r) {
                int base = (r * 64 + c) * 29;
                if (x > 0) s += sF[base + x - 1];
                s += sF[base + x];
                if (x < 27) s += sF[base + x + 1];
            }
            float v = s * (1.f / 9.f);
            int col = cc * 64 + c;
            size_t off = (size_t)(brow + x) * D_ + col;
            u16 h = f2bf(v);
            Ah[off] = h; Al[off] = f2bf(v - bf2f(h));
            float vv = v * v;
            for (int m = 1; m < 64; m <<= 1) vv += __shfl_xor(vv, m, 64);
            if (lane == 0) atomicAdd(&xn[x], vv);
        }
        __syncthreads();
    }

    // ---- pooled2 channels (1024) in 16 chunks of 64, bilinear ----
    for (int cc = 0; cc < 16; ++cc) {
        for (int it = 0; it < 7; ++it) {
            int x = it * 4 + wave, c = lane;
            const float* sp = pooled2 + ((size_t)(b * C2_ + cc * 64 + c)) * 196;
            float sx = x * 0.5f - 0.25f;
            int ix = (int)floorf(sx);
            float fx = sx - ix;
            int x0 = min(max(ix, 0), 13), x1 = min(max(ix + 1, 0), 13);
            float v = (1.f - fy) * ((1.f - fx) * sp[y0 * 14 + x0] + fx * sp[y0 * 14 + x1])
                    + fy * ((1.f - fx) * sp[y1 * 14 + x0] + fx * sp[y1 * 14 + x1]);
            int col = C1_ + cc * 64 + c;
            size_t off = (size_t)(brow + x) * D_ + col;
            u16 h = f2bf(v);
            Ah[off] = h; Al[off] = f2bf(v - bf2f(h));
            float vv = v * v;
            for (int m = 1; m < 64; m <<= 1) vv += __shfl_xor(vv, m, 64);
            if (lane == 0) atomicAdd(&xn[x], vv);
        }
    }
    __syncthreads();
    if (tid < 28) xnorm[brow + tid] = xn[tid];
}

// ---------------- phase-1: bf16 hi-only GEMM, 128x256 tile, value-min ----------
// 32x32x16 MFMA, each wave 64x128 (2x4 acc tiles, 128 acc VGPRs). Per wave-kt:
// 12 ds_read_b128 (~144 cyc) vs 16 MFMA (~620 cyc) -> MFMA-bound. LDS swizzle:
// 16B-chunk slot = chunk ^ ((row>>1)&3): any 16 consecutive lanes of a b128
// fragment read hit all 8 bank-groups 2x (the floor). (R4's `^ (row&3)` key
// collapsed to 4 groups per 16-lane phase -> 4-way conflict; counter showed
// 4 extra cyc/read.) Staging source-side: lane fetches chunk (l&3)^((l>>3)&3).
typedef __bf16 bf16x8 __attribute__((ext_vector_type(8)));
typedef float  f32x4  __attribute__((ext_vector_type(4)));
typedef float  f32x16 __attribute__((ext_vector_type(16)));

__global__ __launch_bounds__(256, 2)
void k_gemm1(const u16* __restrict__ Ah, const u16* __restrict__ Bh,
             const float* __restrict__ ynorm, float* __restrict__ partf) {
    __shared__ u16 sA[128 * 32];       // 8 KB
    __shared__ u16 sB[256 * 32];       // 16 KB
    __shared__ float smin[128][2];

    const int tid = threadIdx.x, lane = tid & 63, wave = tid >> 6;
    // grouped tile order for B locality
    const int GM = 4, nig = GM * NT_;
    const int grp = blockIdx.x / nig, rem = blockIdx.x - grp * nig;
    const int first = grp * GM;
    const int gsz = (MT2_ - first) < GM ? (MT2_ - first) : GM;
    const int mt = first + rem % gsz;
    const int pt = rem / gsz;
    const int p0 = pt * 128, m0 = mt * 256;

    f32x16 acc[2][4];
#pragma unroll
    for (int i = 0; i < 2; ++i)
#pragma unroll
        for (int j = 0; j < 4; ++j)
#pragma unroll
            for (int e = 0; e < 16; ++e) acc[i][j][e] = 0.f;

    const int srow = lane >> 2;                            // 0..15 within span
    const int schunk8 = ((lane & 3) ^ ((lane >> 3) & 3)) * 8;  // source chunk (u16 elems)
    const int wr = (wave >> 1) * 64, wc = (wave & 1) * 128;
    const int rA = lane & 31, kh = lane >> 5;
    const int rsw = (lane >> 1) & 3;                       // read-side swizzle key

    for (int kt = 0; kt < 48; ++kt) {
        const int k0 = kt * 32;
        // ---- stage A (8 spans of 1 KB; 2/wave) and B (16 spans; 4/wave) ----
#pragma unroll
        for (int s = 0; s < 2; ++s) {
            const int span = wave * 2 + s;
            const int row = span * 16 + srow;
            const u16* ga = Ah + (size_t)(p0 + row) * D_ + k0 + schunk8;
            __builtin_amdgcn_global_load_lds((const __attribute__((address_space(1))) void*)ga,
                (__attribute__((address_space(3))) void*)&sA[span * 512], 16, 0, 0);
        }
#pragma unroll
        for (int s = 0; s < 4; ++s) {
            const int span = wave * 4 + s;
            const int row = span * 16 + srow;
            const u16* gb = Bh + (size_t)(m0 + row) * D_ + k0 + schunk8;
            __builtin_amdgcn_global_load_lds((const __attribute__((address_space(1))) void*)gb,
                (__attribute__((address_space(3))) void*)&sB[span * 512], 16, 0, 0);
        }
        __syncthreads();
        bf16x8 af[2][2], bfr[2][4];
#pragma unroll
        for (int ks = 0; ks < 2; ++ks) {
            const int slot = ((ks * 2 + kh) ^ rsw) * 8;
#pragma unroll
            for (int ti = 0; ti < 2; ++ti)
                af[ks][ti] = *(const bf16x8*)&sA[(wr + ti * 32 + rA) * 32 + slot];
#pragma unroll
            for (int tj = 0; tj < 4; ++tj)
                bfr[ks][tj] = *(const bf16x8*)&sB[(wc + tj * 32 + rA) * 32 + slot];
        }
#pragma unroll
        for (int ks = 0; ks < 2; ++ks)
#pragma unroll
            for (int ti = 0; ti < 2; ++ti)
#pragma unroll
                for (int tj = 0; tj < 4; ++tj)
                    acc[ti][tj] = __builtin_amdgcn_mfma_f32_32x32x16_bf16(
                        af[ks][ti], bfr[ks][tj], acc[ti][tj], 0, 0, 0);
        __syncthreads();
    }

    // epilogue: C layout (32x32): col = lane&31, row = (reg&3)+8*(reg>>2)+4*kh
    const int c32 = lane & 31;
    float yn[4];
#pragma unroll
    for (int tj = 0; tj < 4; ++tj) yn[tj] = ynorm[m0 + wc + tj * 32 + c32];
#pragma unroll
    for (int ti = 0; ti < 2; ++ti) {
#pragma unroll
        for (int reg = 0; reg < 16; ++reg) {
            const int rloc = wr + ti * 32 + (reg & 3) + 8 * (reg >> 2) + 4 * kh;
            float v = __uint_as_float(0x7f800000u);
#pragma unroll
            for (int tj = 0; tj < 4; ++tj)
                v = fminf(v, yn[tj] - 2.0f * acc[ti][tj][reg]);
#pragma unroll
            for (int msk = 1; msk < 32; msk <<= 1)
                v = fminf(v, __shfl_xor(v, msk, 64));
            if (c32 == 0) smin[rloc][wave & 1] = v;
        }
    }
    __syncthreads();
    if (tid < 128)
        partf[(size_t)mt * N_ + p0 + tid] = fminf(smin[tid][0], smin[tid][1]);
}

// ---------------- reduce partial mins -> approx patch scores ----------------
__global__ void k_reduce(const float* __restrict__ partf, const float* __restrict__ xnorm,
                         float* __restrict__ ps) {
    int n = blockIdx.x * 128 + threadIdx.x;
    float best = __uint_as_float(0x7f800000u);
    for (int t = 0; t < MT2_; ++t)
        best = fminf(best, partf[(size_t)t * N_ + n]);
    ps[n] = sqrtf(fmaxf(best + xnorm[n], 0.f));
}

// ---------------- per-image approx top-8 patches (candidates) ----------------
__global__ void k_cand(const float* __restrict__ ps, int* __restrict__ candrow) {
    int b = blockIdx.x, tid = threadIdx.x;
    __shared__ u64 red[4];
    u64 prev = ~0ull;
    for (int j = 0; j < 8; ++j) {
        u64 best = 0;
        for (int p = tid; p < P_; p += 256) {
            u64 pk = ((u64)ordf(ps[b * P_ + p]) << 32) | (u32)(~(u32)p);
            if (pk < prev && pk > best) best = pk;
        }
        for (int msk = 1; msk < 64; msk <<= 1) {
            u64 o = __shfl_xor(best, msk, 64);
            best = o > best ? o : best;
        }
        int wave = tid >> 6, lane = tid & 63;
        if (lane == 0) red[wave] = best;
        __syncthreads();
        u64 m = red[0];
        for (int w = 1; w < 4; ++w) m = red[w] > m ? red[w] : m;
        if (tid == 0) candrow[b * 8 + j] = b * P_ + (int)(~(u32)m);
        prev = m;
        __syncthreads();
    }
}

// ---------------- phase-2: exact 3-term split GEMM over 128 candidate rows ----
__global__ __launch_bounds__(256)
void k_gexact(const u16* __restrict__ Ah, const u16* __restrict__ Al,
              const u16* __restrict__ Bh, const u16* __restrict__ Bl,
              const float* __restrict__ ynorm, const int* __restrict__ candrow,
              u64* __restrict__ parte) {
    __shared__ u16 sA[2][128 * 32];
    __shared__ u16 sB[2][128 * 32];
    __shared__ u64 smin[128][2];
    __shared__ int scand[128];

    const int tid = threadIdx.x;
    const int lane = tid & 63, wave = tid >> 6;
    const int mt = blockIdx.x;
    const int m0 = mt * 128;
    if (tid < 128) scand[tid] = candrow[tid];

    f32x16 acc[2][2];
#pragma unroll
    for (int i = 0; i < 2; ++i)
#pragma unroll
        for (int j = 0; j < 2; ++j)
#pragma unroll
            for (int e = 0; e < 16; ++e) acc[i][j][e] = 0.f;

    const int srow = lane >> 2;
    const int scol = ((lane & 3) ^ ((lane >> 3) & 3)) * 8;
    const int wr = (wave >> 1) * 64, wc = (wave & 1) * 64;
    const int rA = lane & 31;
    const int sw = (lane >> 1) & 3;
    __syncthreads();

    for (int kt = 0; kt < 48; ++kt) {
        const int k0 = kt * 32;
#pragma unroll
        for (int s = 0; s < 2; ++s) {
            const int slab = wave * 2 + s;
            const int row = slab * 16 + srow;
            const int grow = scand[row];
            const u16* ga = Ah + (size_t)grow * D_ + k0 + scol;
            __builtin_amdgcn_global_load_lds((const __attribute__((address_space(1))) void*)ga,
                (__attribute__((address_space(3))) void*)&sA[0][slab * 512], 16, 0, 0);
            const u16* ga2 = Al + (size_t)grow * D_ + k0 + scol;
            __builtin_amdgcn_global_load_lds((const __attribute__((address_space(1))) void*)ga2,
                (__attribute__((address_space(3))) void*)&sA[1][slab * 512], 16, 0, 0);
            const u16* gb = Bh + (size_t)(m0 + row) * D_ + k0 + scol;
            __builtin_amdgcn_global_load_lds((const __attribute__((address_space(1))) void*)gb,
                (__attribute__((address_space(3))) void*)&sB[0][slab * 512], 16, 0, 0);
            const u16* gb2 = Bl + (size_t)(m0 + row) * D_ + k0 + scol;
            __builtin_amdgcn_global_load_lds((const __attribute__((address_space(1))) void*)gb2,
                (__attribute__((address_space(3))) void*)&sB[1][slab * 512], 16, 0, 0);
        }
        __syncthreads();
#pragma unroll
        for (int ks = 0; ks < 2; ++ks) {
            const int co = ((ks * 2 + (lane >> 5)) ^ sw) * 8;
            bf16x8 ah0 = *(const bf16x8*)&sA[0][(wr + rA) * 32 + co];
            bf16x8 ah1 = *(const bf16x8*)&sA[0][(wr + 32 + rA) * 32 + co];
            bf16x8 al0 = *(const bf16x8*)&sA[1][(wr + rA) * 32 + co];
            bf16x8 al1 = *(const bf16x8*)&sA[1][(wr + 32 + rA) * 32 + co];
            bf16x8 bh0 = *(const bf16x8*)&sB[0][(wc + rA) * 32 + co];
            bf16x8 bh1 = *(const bf16x8*)&sB[0][(wc + 32 + rA) * 32 + co];
            bf16x8 bl0 = *(const bf16x8*)&sB[1][(wc + rA) * 32 + co];
            bf16x8 bl1 = *(const bf16x8*)&sB[1][(wc + 32 + rA) * 32 + co];
            acc[0][0] = __builtin_amdgcn_mfma_f32_32x32x16_bf16(ah0, bh0, acc[0][0], 0, 0, 0);
            acc[0][1] = __builtin_amdgcn_mfma_f32_32x32x16_bf16(ah0, bh1, acc[0][1], 0, 0, 0);
            acc[1][0] = __builtin_amdgcn_mfma_f32_32x32x16_bf16(ah1, bh0, acc[1][0], 0, 0, 0);
            acc[1][1] = __builtin_amdgcn_mfma_f32_32x32x16_bf16(ah1, bh1, acc[1][1], 0, 0, 0);
            acc[0][0] = __builtin_amdgcn_mfma_f32_32x32x16_bf16(ah0, bl0, acc[0][0], 0, 0, 0);
            acc[0][1] = __builtin_amdgcn_mfma_f32_32x32x16_bf16(ah0, bl1, acc[0][1], 0, 0, 0);
            acc[1][0] = __builtin_amdgcn_mfma_f32_32x32x16_bf16(ah1, bl0, acc[1][0], 0, 0, 0);
            acc[1][1] = __builtin_amdgcn_mfma_f32_32x32x16_bf16(ah1, bl1, acc[1][1], 0, 0, 0);
            acc[0][0] = __builtin_amdgcn_mfma_f32_32x32x16_bf16(al0, bh0, acc[0][0], 0, 0, 0);
            acc[0][1] = __builtin_amdgcn_mfma_f32_32x32x16_bf16(al0, bh1, acc[0][1], 0, 0, 0);
            acc[1][0] = __builtin_amdgcn_mfma_f32_32x32x16_bf16(al1, bh0, acc[1][0], 0, 0, 0);
            acc[1][1] = __builtin_amdgcn_mfma_f32_32x32x16_bf16(al1, bh1, acc[1][1], 0, 0, 0);
        }
        __syncthreads();
    }

    const int wrB = wave >> 1, wcB = wave & 1;
    const int half = lane >> 5, c32 = lane & 31;
    float yn[2];
    yn[0] = ynorm[m0 + wcB * 64 + c32];
    yn[1] = ynorm[m0 + wcB * 64 + 32 + c32];
#pragma unroll
    for (int ti = 0; ti < 2; ++ti) {
#pragma unroll
        for (int reg = 0; reg < 16; ++reg) {
            const int rloc = wrB * 64 + ti * 32 + 4 * half + (reg & 3) + 8 * (reg >> 2);
            u64 best = ~0ull;
#pragma unroll
            for (int tj = 0; tj < 2; ++tj) {
                float v = yn[tj] - 2.0f * acc[ti][tj][reg];
                u32 col = (u32)(m0 + wcB * 64 + tj * 32 + c32);
                u64 pk = ((u64)ordf(v) << 32) | col;
                best = pk < best ? pk : best;
            }
#pragma unroll
            for (int msk = 1; msk < 32; msk <<= 1) {
                u64 o = __shfl_xor(best, msk, 64);
                best = o < best ? o : best;
            }
            if (c32 == 0) smin[rloc][wcB] = best;
        }
    }
    __syncthreads();
    if (tid < 128) {
        u64 a = smin[tid][0], b = smin[tid][1];
        parte[(size_t)mt * 128 + tid] = a < b ? a : b;
    }
}

// ---------------- pick exact winner per image ----------------
__global__ void k_pick(const u64* __restrict__ parte, const float* __restrict__ xnorm,
                       const int* __restrict__ candrow, int* __restrict__ mprow,
                       int* __restrict__ nnidx, float* __restrict__ score) {
    __shared__ float sps[128];
    __shared__ int sloc[128];
    int i = threadIdx.x;   // 0..127
    u64 best = ~0ull;
    for (int t = 0; t < MT1_; ++t) {
        u64 v = parte[(size_t)t * 128 + i];
        best = v < best ? v : best;
    }
    float val = unordf((u32)(best >> 32)) + xnorm[candrow[i]];
    sps[i] = sqrtf(fmaxf(val, 0.f));
    sloc[i] = (int)(u32)best;
    __syncthreads();
    if (i < B_) {
        float bs = -1.f; int bj = 0; int brw = 1 << 30;
        for (int j = 0; j < 8; ++j) {
            int idx = i * 8 + j;
            float v = sps[idx];
            int row = candrow[idx];
            if (v > bs || (v == bs && row < brw)) { bs = v; bj = idx; brw = row; }
        }
        mprow[i] = brw;
        nnidx[i] = sloc[bj];
        score[i] = bs;
    }
}

// ---------------- d_nb: dist(bank[nn_index[b]], bank) exact fp32 ----------------
__global__ void k_dnb(const float* __restrict__ bank, const float* __restrict__ ynorm,
                      const int* __restrict__ nnidx, float* __restrict__ dnb) {
    int wave = threadIdx.x >> 6, lane = threadIdx.x & 63;
    int m = blockIdx.x * 4 + wave;
    if (m >= M_) return;
    const float4* br = (const float4*)(bank + (size_t)m * D_);
    float acc[B_];
#pragma unroll
    for (int b = 0; b < B_; ++b) acc[b] = 0.f;
#pragma unroll
    for (int p = 0; p < 6; ++p) {
        float4 c = br[p * 64 + lane];
#pragma unroll
        for (int b = 0; b < B_; ++b) {
            const float4* nr = (const float4*)(bank + (size_t)nnidx[b] * D_);
            float4 a = nr[p * 64 + lane];
            acc[b] += a.x * c.x + a.y * c.y + a.z * c.z + a.w * c.w;
        }
    }
    float ym = ynorm[m];
    float keep = 0.f;
#pragma unroll
    for (int b = 0; b < B_; ++b) {
        float v = acc[b];
        for (int msk = 1; msk < 64; msk <<= 1) v += __shfl_xor(v, msk, 64);
        if (lane == b) keep = v;
    }
    if (lane < B_) {
        float ynn = ynorm[nnidx[lane]];
        dnb[lane * M_ + m] = sqrtf(fmaxf(ynn - 2.f * keep + ym, 0.f));
    }
}

// ---------------- top-9 smallest of dnb, two-stage exact ----------------
// stage 1: 128 blocks, each top-9 of a 1875-chunk (monotone extraction: next
// smallest packed value strictly greater than prev -> no chosen-list scan).
__global__ void k_top9a(const float* __restrict__ dnb, u64* __restrict__ cand9) {
    int blk = blockIdx.x;            // b*8 + chunk
    int b = blk >> 3, ch = blk & 7;
    int base = ch * 1875;
    int tid = threadIdx.x;
    __shared__ u64 red[4];
    u64 prev = 0;
    for (int p = 0; p < 9; ++p) {
        u64 best = ~0ull;
        for (int i = tid; i < 1875; i += 256) {
            float v = dnb[b * M_ + base + i];
            u64 pk = ((u64)ordf(v) << 32) | (u32)(base + i);
            if (pk > prev && pk < best) best = pk;
        }
        for (int msk = 1; msk < 64; msk <<= 1) {
            u64 o = __shfl_xor(best, msk, 64);
            best = o < best ? o : best;
        }
        int wave = tid >> 6, lane = tid & 63;
        if (lane == 0) red[wave] = best;
        __syncthreads();
        u64 m = red[0];
        for (int w = 1; w < 4; ++w) m = red[w] < m ? red[w] : m;
        if (tid == 0) cand9[blk * 9 + p] = m;
        prev = m;
        __syncthreads();
    }
}
// stage 2: merge 8x9=72 candidates per image -> global top-9 (exact)
__global__ void k_top9b(const u64* __restrict__ cand9, int* __restrict__ support) {
    int b = blockIdx.x, lane = threadIdx.x;   // 64 threads
    u64 v0 = lane < 72 ? cand9[b * 72 + lane] : ~0ull;
    u64 v1 = (lane + 64) < 72 ? cand9[b * 72 + lane + 64] : ~0ull;
    u64 prev = 0;
    for (int p = 0; p < 9; ++p) {
        u64 best = ~0ull;
        if (v0 > prev && v0 < best) best = v0;
        if (v1 > prev && v1 < best) best = v1;
        for (int msk = 1; msk < 64; msk <<= 1) {
            u64 o = __shfl_xor(best, msk, 64);
            best = o < best ? o : best;
        }
        if (lane == 0) support[b * 9 + p] = (int)(u32)best;
        prev = best;
    }
}

// ---------------- d2 + softmax reweight -> pred_score ----------------
__global__ void k_final(const u16* __restrict__ Ah, const u16* __restrict__ Al,
                        const float* __restrict__ bank, const float* __restrict__ ynorm,
                        const float* __restrict__ xnorm, const int* __restrict__ mprow,
                        const int* __restrict__ support, const float* __restrict__ score,
                        float* __restrict__ out_score) {
    int b = blockIdx.x;
    int wave = threadIdx.x >> 6, lane = threadIdx.x & 63;
    __shared__ float d2s[9];
    int row = mprow[b];
    float xn = xnorm[row];
    for (int s = wave; s < 9; s += 4) {
        int sup = support[b * 9 + s];
        float acc = 0.f;
        for (int p = 0; p < 24; ++p) {
            int k = p * 64 + lane;
            float e = bf2f(Ah[(size_t)row * D_ + k]) + bf2f(Al[(size_t)row * D_ + k]);
            acc += e * bank[(size_t)sup * D_ + k];
        }
        for (int msk = 1; msk < 64; msk <<= 1) acc += __shfl_xor(acc, msk, 64);
        if (lane == 0) d2s[s] = sqrtf(fmaxf(xn - 2.f * acc + ynorm[sup], 0.f));
    }
    __syncthreads();
    if (threadIdx.x == 0) {
        float mx = d2s[0];
        for (int i = 1; i < 9; ++i) mx = fmaxf(mx, d2s[i]);
        float den = 0.f;
        for (int i = 0; i < 9; ++i) den += expf(d2s[i] - mx);
        float w = 1.f - expf(d2s[0] - mx) / den;
        out_score[b] = w * score[b];
    }
}

// ---------------- bilinear upsample 28->224 ----------------
__global__ void k_upsample(const float* __restrict__ ps, float* __restrict__ U) {
    int idx = blockIdx.x * 256 + threadIdx.x;
    if (idx >= B_ * IMG_ * IMG_) return;
    int x = idx % IMG_, y = (idx / IMG_) % IMG_, b = idx / (IMG_ * IMG_);
    float sx = x * 0.125f - 0.4375f, sy = y * 0.125f - 0.4375f;
    int ix = (int)floorf(sx), iy = (int)floorf(sy);
    float fx = sx - ix, fy = sy - iy;
    int x0 = min(max(ix, 0), 27), x1 = min(max(ix + 1, 0), 27);
    int y0 = min(max(iy, 0), 27), y1 = min(max(iy + 1, 0), 27);
    const float* p = ps + b * P_;
    U[idx] = (1.f - fy) * ((1.f - fx) * p[y0 * 28 + x0] + fx * p[y0 * 28 + x1])
           + fy * ((1.f - fx) * p[y1 * 28 + x0] + fx * p[y1 * 28 + x1]);
}

// ---------------- separable gaussian blur, reflect pad ----------------
__global__ void k_blurh(const float* __restrict__ U, float* __restrict__ T) {
    __shared__ float g[KS_];
    __shared__ float gs;
    int tid = threadIdx.x;
    if (tid < KS_) { float d = tid - 16.f; g[tid] = expf(-(d * d) / 32.0f); }
    __syncthreads();
    if (tid == 0) { float s = 0.f; for (int i = 0; i < KS_; ++i) s += g[i]; gs = 1.f / s; }
    __syncthreads();
    int idx = blockIdx.x * 256 + tid;
    if (idx >= B_ * IMG_ * IMG_) return;
    int x = idx % IMG_, rowbase = idx - x;
    float a = 0.f;
    for (int t = 0; t < KS_; ++t) {
        int xx = x + t - 16;
        xx = xx < 0 ? -xx : (xx > 223 ? 446 - xx : xx);
        a += g[t] * U[rowbase + xx];
    }
    T[idx] = a * gs;
}
__global__ void k_blurv(const float* __restrict__ T, float* __restrict__ out) {
    __shared__ float g[KS_];
    __shared__ float gs;
    int tid = threadIdx.x;
    if (tid < KS_) { float d = tid - 16.f; g[tid] = expf(-(d * d) / 32.0f); }
    __syncthreads();
    if (tid == 0) { float s = 0.f; for (int i = 0; i < KS_; ++i) s += g[i]; gs = 1.f / s; }
    __syncthreads();
    int idx = blockIdx.x * 256 + tid;
    if (idx >= B_ * IMG_ * IMG_) return;
    int x = idx % IMG_, y = (idx / IMG_) % IMG_, b = idx / (IMG_ * IMG_);
    float a = 0.f;
    for (int t = 0; t < KS_; ++t) {
        int yy = y + t - 16;
        yy = yy < 0 ? -yy : (yy > 223 ? 446 - yy : yy);
        a += g[t] * T[(b * IMG_ + yy) * IMG_ + x];
    }
    out[idx] = a * gs;
}

// ---------------- launch ----------------
extern "C" void kernel_launch(void* const* d_in, const int* in_sizes, int n_in,
                              void* d_out, int out_size, void* d_ws, size_t ws_size,
                              hipStream_t stream) {
    const float* feat1 = (const float*)d_in[0];
    const float* feat2 = (const float*)d_in[1];
    const float* bank  = (const float*)d_in[2];
    float* out = (float*)d_out;
    char* ws = (char*)d_ws;

    size_t o = 0;
    u16* Ah = (u16*)(ws + o); o += (size_t)N_ * D_ * 2;
    u16* Al = (u16*)(ws + o); o += (size_t)N_ * D_ * 2;
    size_t o_Bh = o;
    u16* Bh = (u16*)(ws + o); o += (size_t)MPAD_ * D_ * 2;
    u16* Bl = (u16*)(ws + o); o += (size_t)MPAD_ * D_ * 2;
    // scratch union: pooled2 (pre-GEMM) / partf (GEMM phase)
    size_t o_scr = o;
    float* pooled2 = (float*)(ws + o_scr);
    float* partf   = (float*)(ws + o_scr);
    size_t r1 = (size_t)MT2_ * N_ * 4, r2 = (size_t)B_ * C2_ * 196 * 4;
    o += (r1 > r2 ? r1 : r2);
    float* xnorm = (float*)(ws + o); o += (size_t)N_ * 4;
    float* ynorm = (float*)(ws + o); o += (size_t)MPAD_ * 4;
    float* ps    = (float*)(ws + o); o += (size_t)N_ * 4;
    int* candrow = (int*)(ws + o);   o += 512;
    u64* parte   = (u64*)(ws + o);   o += (size_t)MT1_ * 128 * 8;
    float* dnb   = (float*)(ws + o); o += (size_t)B_ * M_ * 4;
    u64* cand9   = (u64*)(ws + o);   o += 128 * 9 * 8;
    int*   mprow = (int*)(ws + o);   o += 64;
    int*   nnidx = (int*)(ws + o);   o += 64;
    float* score = (float*)(ws + o); o += 64;
    int* support = (int*)(ws + o);   o += 9 * B_ * 4;
    // U/T alias the Bh/Bl region (dead after k_gexact)
    float* U = (float*)(ws + o_Bh);
    float* T = (float*)(ws + o_Bh + (size_t)B_ * IMG_ * IMG_ * 4);

    k_pool2<<<(B_ * C2_ * H2_ * H2_ + 255) / 256, 256, 0, stream>>>(feat2, pooled2);
    k_bank<<<MPAD_, 192, 0, stream>>>(bank, Bh, Bl, ynorm);
    k_embed<<<B_ * 28, 256, 0, stream>>>(feat1, pooled2, Ah, Al, xnorm);
    k_gemm1<<<MT2_ * NT_, 256, 0, stream>>>(Ah, Bh, ynorm, partf);
    k_reduce<<<NT_, 128, 0, stream>>>(partf, xnorm, ps);
    k_cand<<<B_, 256, 0, stream>>>(ps, candrow);
    k_gexact<<<MT1_, 256, 0, stream>>>(Ah, Al, Bh, Bl, ynorm, candrow, parte);
    k_pick<<<1, 128, 0, stream>>>(parte, xnorm, candrow, mprow, nnidx, score);
    k_dnb<<<(M_ + 3) / 4, 256, 0, stream>>>(bank, ynorm, nnidx, dnb);
    k_top9a<<<128, 256, 0, stream>>>(dnb, cand9);
    k_top9b<<<B_, 64, 0, stream>>>(cand9, support);
    k_final<<<B_, 256, 0, stream>>>(Ah, Al, bank, ynorm, xnorm, mprow, support, score,
                                    out + (size_t)B_ * IMG_ * IMG_);
    k_upsample<<<(B_ * IMG_ * IMG_ + 255) / 256, 256, 0, stream>>>(ps, U);
    k_blurh<<<(B_ * IMG_ * IMG_ + 255) / 256, 256, 0, stream>>>(U, T);
    k_blurv<<<(B_ * IMG_ * IMG_ + 255) / 256, 256, 0, stream>>>(T, out);
}